// Round 1
// baseline (282.486 us; speedup 1.0000x reference)
//
#include <hip/hip_runtime.h>
#include <hip/hip_bf16.h>

typedef __attribute__((ext_vector_type(8))) unsigned short us8;
typedef __attribute__((ext_vector_type(8))) __bf16 bf16x8;
typedef __attribute__((ext_vector_type(4))) float f32x4;

__device__ __forceinline__ unsigned short f2bf(float f) {
  unsigned int u = __float_as_uint(f);
  u += 0x7FFFu + ((u >> 16) & 1u);   // round-to-nearest-even
  return (unsigned short)(u >> 16);
}

// ---------------------------------------------------------------------------
// ws layout (bytes)
//   Apad : [2][132][132][256] bf16  (conv1 out, zero halo of 2) = 17,842,176
//   BT   : [256][6400] bf16  (Wp transposed to [n][k], k=(dh*5+dw)*256+c)
//   P    : [32768][256] f32  (primary capsules, NHWC)
// ---------------------------------------------------------------------------
#define APAD_BYTES 17842176
#define BT_OFF     17842176
#define P_OFF      21118976
// total = 54,673,408 bytes

// --- K0: weight prep: BT[n][k] = bf16(Wp[n][c][dh][dw]), k = dhw*256 + c ---
__global__ __launch_bounds__(256) void prep_w(const float* __restrict__ Wp,
                                              unsigned short* __restrict__ BT) {
  int idx = blockIdx.x * 256 + threadIdx.x;        // 256*6400 total
  int n = idx / 6400;
  int k = idx - n * 6400;
  int dhw = k >> 8;          // 0..24
  int c = k & 255;
  BT[idx] = f2bf(Wp[(n * 256 + c) * 25 + dhw]);
}

// --- K1: conv1 = relu(conv5x5(x, W1)+b1), write padded NHWC bf16 -----------
__global__ __launch_bounds__(256) void conv1_k(const float* __restrict__ x,
                                               const float* __restrict__ W1,
                                               const float* __restrict__ b1,
                                               unsigned short* __restrict__ Apad) {
  int t = threadIdx.x;
  int pxt = blockIdx.x >> 3;                 // 512 pixel tiles of 64
  int cq  = blockIdx.x & 7;                  // 8 channel quads of 32
  int px  = (pxt << 6) + (t & 63);           // same (b,h) across the tile
  int cg  = __builtin_amdgcn_readfirstlane(t >> 6);   // wave-uniform
  int co0 = (cq << 5) + (cg << 3);           // 8 channels per thread
  int b = px >> 14, hw = px & 16383;
  int h = hw >> 7, w = hw & 127;

  float patch[25];
#pragma unroll
  for (int dh = 0; dh < 5; ++dh)
#pragma unroll
    for (int dw = 0; dw < 5; ++dw) {
      int hh = h + dh - 2, ww = w + dw - 2;
      bool ok = (hh >= 0) & (hh < 128) & (ww >= 0) & (ww < 128);
      patch[dh * 5 + dw] = ok ? x[(b << 14) + hh * 128 + ww] : 0.f;
    }
  us8 o;
#pragma unroll
  for (int c = 0; c < 8; ++c) {
    float acc = b1[co0 + c];
#pragma unroll
    for (int i = 0; i < 25; ++i) acc += patch[i] * W1[(co0 + c) * 25 + i];
    o[c] = f2bf(fmaxf(acc, 0.f));
  }
  *(us8*)(Apad + (size_t)((b * 132 + h + 2) * 132 + (w + 2)) * 256 + co0) = o;
}

// --- K2: big conv as implicit GEMM + fused /32 + bias + squash -------------
// M = 32768 pixels, N = 256 out-chan, K = 6400 = 25 taps * 256 c
// tile 128x128, 4 waves of 64x64, BK=32 (one (dh,dw), 32 channels per step)
#define LDK 40   // 32 + 8 pad (bf16 elems): 80B rows -> ~2-way conflicts (free)

__global__ __launch_bounds__(256) void caps_conv2(
    const unsigned short* __restrict__ A,   // Apad NHWC bf16
    const unsigned short* __restrict__ BT,  // [256][6400] bf16
    const float* __restrict__ bp,           // [256]
    const float* __restrict__ cbp,          // [256] (=32x8 flat)
    float* __restrict__ P)                  // [32768][256] f32
{
  __shared__ __attribute__((aligned(16))) unsigned short As[128 * LDK];
  __shared__ __attribute__((aligned(16))) unsigned short Bs[128 * LDK];

  const int tid = threadIdx.x;
  const int bm = blockIdx.x & 255;
  const int bn = blockIdx.x >> 8;           // 0..1
  const int m0 = bm << 7, n0 = bn << 7;

  // staging role: rows sr and sr+64, 16B part sp
  const int sr = tid >> 2;
  const int sp = tid & 3;

  int abase[2], bbase[2];
#pragma unroll
  for (int q = 0; q < 2; ++q) {
    int m = m0 + sr + q * 64;
    int b = m >> 14, hw = m & 16383;
    int h = hw >> 7, w = hw & 127;
    abase[q] = ((b * 132 + h) * 132 + w) * 256;     // pad offset comes via dh,dw
    bbase[q] = (n0 + sr + q * 64) * 6400;
  }

  const int lane = tid & 63;
  const int wid = tid >> 6;
  const int wm = wid >> 1, wn = wid & 1;
  const int arow = wm * 64 + (lane & 15);
  const int brow = wn * 64 + (lane & 15);
  const int fragoff = (lane >> 4) * 8;

  f32x4 acc[4][4] = {};

  for (int t = 0; t < 200; ++t) {
    const int dhw = t >> 3;
    const int coff = (t & 7) << 5;
    const int dh = dhw / 5, dw = dhw - dh * 5;
    const int aoff = ((dh * 132 + dw) << 8) + coff + sp * 8;
    const int kpos = (t << 5) + sp * 8;

    us8 areg[2], breg[2];
#pragma unroll
    for (int q = 0; q < 2; ++q) {
      areg[q] = *(const us8*)(A + abase[q] + aoff);
      breg[q] = *(const us8*)(BT + bbase[q] + kpos);
    }
    __syncthreads();
#pragma unroll
    for (int q = 0; q < 2; ++q) {
      *(us8*)(&As[(sr + q * 64) * LDK + sp * 8]) = areg[q];
      *(us8*)(&Bs[(sr + q * 64) * LDK + sp * 8]) = breg[q];
    }
    __syncthreads();

    bf16x8 af[4], bf[4];
#pragma unroll
    for (int s = 0; s < 4; ++s) {
      af[s] = *(const bf16x8*)(&As[(arow + s * 16) * LDK + fragoff]);
      bf[s] = *(const bf16x8*)(&Bs[(brow + s * 16) * LDK + fragoff]);
    }
#pragma unroll
    for (int i = 0; i < 4; ++i)
#pragma unroll
      for (int j = 0; j < 4; ++j)
        acc[i][j] = __builtin_amdgcn_mfma_f32_16x16x32_bf16(af[i], bf[j], acc[i][j], 0, 0, 0);
  }

  // epilogue: v = conv/32 + (bp/32 + cbp); squash over 8 atoms (= 8 adjacent lanes)
  const int r4 = (lane >> 4) << 2;
  const int cl = lane & 15;
#pragma unroll
  for (int j = 0; j < 4; ++j) {
    int col = n0 + wn * 64 + j * 16 + cl;
    float cc = bp[col] * (1.f / 32.f) + cbp[col];
#pragma unroll
    for (int i = 0; i < 4; ++i) {
      int mrow = m0 + wm * 64 + i * 16 + r4;
#pragma unroll
      for (int e = 0; e < 4; ++e) {
        float v = acc[i][j][e] * (1.f / 32.f) + cc;
        float s = v * v;
        s += __shfl_xor(s, 1);
        s += __shfl_xor(s, 2);
        s += __shfl_xor(s, 4);
        float scale = s / ((1.f + s) * sqrtf(s + 1e-9f));
        P[(size_t)(mrow + e) * 256 + col] = v * scale;
      }
    }
  }
}

// --- K3: per-pixel tail: seg caps (routing is identity) + length + recon ---
__global__ __launch_bounds__(64) void tail_k(
    const float* __restrict__ P, const float* __restrict__ y,
    const float* __restrict__ Ws, const float* __restrict__ bs,
    const float* __restrict__ cbs,
    const float* __restrict__ Wr1, const float* __restrict__ br1,
    const float* __restrict__ Wr2, const float* __restrict__ br2,
    const float* __restrict__ Wr3, const float* __restrict__ br3,
    float* __restrict__ out) {
  int m = blockIdx.x * 64 + threadIdx.x;   // 32768 pixels

  // P8[c] = sum over 32 capsules of primary[i][c]
  float4 p0 = {0, 0, 0, 0}, p1 = {0, 0, 0, 0};
  const float4* Pr = (const float4*)(P + (size_t)m * 256);
#pragma unroll 8
  for (int i = 0; i < 32; ++i) {
    float4 a = Pr[2 * i], b = Pr[2 * i + 1];
    p0.x += a.x; p0.y += a.y; p0.z += a.z; p0.w += a.w;
    p1.x += b.x; p1.y += b.y; p1.z += b.z; p1.w += b.w;
  }
  float P8[8] = {p0.x, p0.y, p0.z, p0.w, p1.x, p1.y, p1.z, p1.w};

  // seg preact + squash
  float pre[16];
  float sq = 0.f;
#pragma unroll
  for (int a = 0; a < 16; ++a) {
    float s = 32.f * bs[a] + cbs[a];
#pragma unroll
    for (int c = 0; c < 8; ++c) s += P8[c] * Ws[a * 8 + c];
    pre[a] = s;
    sq += s * s;
  }
  float scale = sq / ((1.f + sq) * sqrtf(sq + 1e-9f));
  out[m] = sqrtf(sq * scale * scale + 1e-9f);     // out_seg

  float yv = y[m];
  float msk[16];
#pragma unroll
  for (int a = 0; a < 16; ++a) msk[a] = pre[a] * scale * yv;

  float r1[64];
#pragma unroll
  for (int j = 0; j < 64; ++j) {
    float s = br1[j];
#pragma unroll
    for (int a = 0; a < 16; ++a) s += msk[a] * Wr1[j * 16 + a];
    r1[j] = fmaxf(s, 0.f);
  }
  float acc = br3[0];
#pragma unroll 2
  for (int k = 0; k < 128; ++k) {
    float s = br2[k];
#pragma unroll
    for (int j = 0; j < 64; ++j) s += r1[j] * Wr2[(k << 6) + j];
    acc += fmaxf(s, 0.f) * Wr3[k];
  }
  out[32768 + m] = 1.f / (1.f + expf(-acc));      // out_recon
}

// ---------------------------------------------------------------------------
extern "C" void kernel_launch(void* const* d_in, const int* in_sizes, int n_in,
                              void* d_out, int out_size, void* d_ws, size_t ws_size,
                              hipStream_t stream) {
  const float* x   = (const float*)d_in[0];
  const float* y   = (const float*)d_in[1];
  const float* W1  = (const float*)d_in[2];
  const float* b1  = (const float*)d_in[3];
  const float* Wp  = (const float*)d_in[4];
  const float* bp  = (const float*)d_in[5];
  const float* cbp = (const float*)d_in[6];
  const float* Ws  = (const float*)d_in[7];
  const float* bs  = (const float*)d_in[8];
  const float* cbs = (const float*)d_in[9];
  const float* Wr1 = (const float*)d_in[10];
  const float* br1 = (const float*)d_in[11];
  const float* Wr2 = (const float*)d_in[12];
  const float* br2 = (const float*)d_in[13];
  const float* Wr3 = (const float*)d_in[14];
  const float* br3 = (const float*)d_in[15];
  float* out = (float*)d_out;

  char* ws = (char*)d_ws;
  unsigned short* Apad = (unsigned short*)ws;
  unsigned short* BT   = (unsigned short*)(ws + BT_OFF);
  float* P             = (float*)(ws + P_OFF);

  hipMemsetAsync(Apad, 0, APAD_BYTES, stream);   // zero halo (and interior)
  hipLaunchKernelGGL(prep_w, dim3(6400), dim3(256), 0, stream, Wp, BT);
  hipLaunchKernelGGL(conv1_k, dim3(4096), dim3(256), 0, stream, x, W1, b1, Apad);
  hipLaunchKernelGGL(caps_conv2, dim3(512), dim3(256), 0, stream, Apad, BT, bp, cbp, P);
  hipLaunchKernelGGL(tail_k, dim3(512), dim3(64), 0, stream,
                     P, y, Ws, bs, cbs, Wr1, br1, Wr2, br2, Wr3, br3, out);
}

// Round 2
// 222.721 us; speedup vs baseline: 1.2683x; 1.2683x over previous
//
#include <hip/hip_runtime.h>
#include <hip/hip_bf16.h>

typedef __attribute__((ext_vector_type(8))) unsigned short us8;
typedef __attribute__((ext_vector_type(8))) __bf16 bf16x8;
typedef __attribute__((ext_vector_type(4))) float f32x4;

__device__ __forceinline__ unsigned short f2bf(float f) {
  unsigned int u = __float_as_uint(f);
  u += 0x7FFFu + ((u >> 16) & 1u);   // round-to-nearest-even
  return (unsigned short)(u >> 16);
}
__device__ __forceinline__ float bf2f(unsigned short u) {
  return __uint_as_float(((unsigned int)u) << 16);
}

// direct global->LDS DMA, 16B per lane (dest = wave-uniform base + lane*16)
__device__ __forceinline__ void gld16(const unsigned short* g, unsigned short* l) {
  __builtin_amdgcn_global_load_lds(reinterpret_cast<const unsigned int*>(g),
                                   reinterpret_cast<unsigned int*>(l), 16, 0, 0);
}

// ---------------------------------------------------------------------------
// ws layout (bytes)
//   Apad : [2][132][132][256] bf16  (conv1 out, zero halo of 2) = 17,842,176
//   BT   : [256][6400] bf16  (Wp transposed to [n][k], k=(dh*5+dw)*256+c)
//   Pp   : 2 x [32768][256] bf16 partials (split-K halves) = 33,554,432
// total = 54,673,408 bytes (same as round-1 footprint)
// ---------------------------------------------------------------------------
#define APAD_BYTES 17842176
#define BT_OFF     17842176
#define PP_OFF     21118976

// --- K0: weight prep: BT[n][k] = bf16(Wp[n][c][dh][dw]), k = dhw*256 + c ---
__global__ __launch_bounds__(256) void prep_w(const float* __restrict__ Wp,
                                              unsigned short* __restrict__ BT) {
  int idx = blockIdx.x * 256 + threadIdx.x;        // 256*6400 total
  int n = idx / 6400;
  int k = idx - n * 6400;
  int dhw = k >> 8;          // 0..24
  int c = k & 255;
  BT[idx] = f2bf(Wp[(n * 256 + c) * 25 + dhw]);
}

// --- K1: conv1 = relu(conv5x5(x, W1)+b1), write padded NHWC bf16 -----------
__global__ __launch_bounds__(256) void conv1_k(const float* __restrict__ x,
                                               const float* __restrict__ W1,
                                               const float* __restrict__ b1,
                                               unsigned short* __restrict__ Apad) {
  int t = threadIdx.x;
  int pxt = blockIdx.x >> 3;                 // 512 pixel tiles of 64
  int cq  = blockIdx.x & 7;                  // 8 channel quads of 32
  int px  = (pxt << 6) + (t & 63);           // same (b,h) across the tile
  int cg  = __builtin_amdgcn_readfirstlane(t >> 6);   // wave-uniform
  int co0 = (cq << 5) + (cg << 3);           // 8 channels per thread
  int b = px >> 14, hw = px & 16383;
  int h = hw >> 7, w = hw & 127;

  float patch[25];
#pragma unroll
  for (int dh = 0; dh < 5; ++dh)
#pragma unroll
    for (int dw = 0; dw < 5; ++dw) {
      int hh = h + dh - 2, ww = w + dw - 2;
      bool ok = (hh >= 0) & (hh < 128) & (ww >= 0) & (ww < 128);
      patch[dh * 5 + dw] = ok ? x[(b << 14) + hh * 128 + ww] : 0.f;
    }
  us8 o;
#pragma unroll
  for (int c = 0; c < 8; ++c) {
    float acc = b1[co0 + c];
#pragma unroll
    for (int i = 0; i < 25; ++i) acc += patch[i] * W1[(co0 + c) * 25 + i];
    o[c] = f2bf(fmaxf(acc, 0.f));
  }
  *(us8*)(Apad + (size_t)((b * 132 + h + 2) * 132 + (w + 2)) * 256 + co0) = o;
}

// --- K2: big conv as implicit GEMM, split-K=2, global_load_lds staging -----
// M = 32768 pixels, N = 256 out-chan, K = 6400 = 25 taps * 256 c
// tile 128x128, 4 waves of 64x64, BK=32; grid = 2 kid x 2 bn x 256 bm = 1024
// LDS linear [128][32] bf16; XOR part-swizzle on (global source, frag read).
__global__ __launch_bounds__(256) void caps_conv2(
    const unsigned short* __restrict__ A,   // Apad NHWC bf16
    const unsigned short* __restrict__ BT,  // [256][6400] bf16
    unsigned short* __restrict__ Pp)        // 2 x [32768][256] bf16 partials
{
  __shared__ __attribute__((aligned(16))) unsigned short As[4096];
  __shared__ __attribute__((aligned(16))) unsigned short Bs[4096];

  const int tid = threadIdx.x;
  const int bid = blockIdx.x;
  // bijective XCD-chunked swizzle (1024 % 8 == 0), bm-major logical order
  const int lid = (bid & 7) * 128 + (bid >> 3);
  const int bm = lid >> 2;
  const int bn = (lid >> 1) & 1;
  const int kid = lid & 1;
  const int m0 = bm << 7, n0 = bn << 7;

  // staging role: row srow (+64 for round 1), swizzled 16B part
  const int srow = tid >> 2;                              // 0..63
  const int p8 = (((tid & 3) ^ ((tid >> 3) & 3)) << 3);   // XOR-swizzled part *8

  int abase[2], bbase[2];
#pragma unroll
  for (int qr = 0; qr < 2; ++qr) {
    int m = m0 + srow + qr * 64;
    int b = m >> 14, hw = m & 16383;
    int h = hw >> 7, w = hw & 127;
    abase[qr] = ((b * 132 + h) * 132 + w) * 256 + p8;
    bbase[qr] = (n0 + srow + qr * 64) * 6400 + p8;
  }
  const int wbase = __builtin_amdgcn_readfirstlane((tid >> 6) << 9);  // wave*512 ushorts

  const int lane = tid & 63;
  const int wid = tid >> 6;
  const int wm = wid >> 1, wn = wid & 1;
  const int rl = lane & 15, q = lane >> 4;
  const int qs = ((q ^ ((rl >> 1) & 3)) << 3);            // swizzled read part *8
  const int aoffr = (wm * 64 + rl) * 32 + qs;
  const int boffr = (wn * 64 + rl) * 32 + qs;

  f32x4 acc[4][4] = {};

  const int t0 = kid * 100;
  for (int t = t0; t < t0 + 100; ++t) {
    const int dhw = t >> 3;
    const int coff = (t & 7) << 5;
    const int dh = dhw / 5, dw = dhw - dh * 5;
    const int aoff = ((dh * 132 + dw) << 8) + coff;
    const int kpos = t << 5;

    gld16(A + abase[0] + aoff, As + wbase);
    gld16(A + abase[1] + aoff, As + 2048 + wbase);
    gld16(BT + bbase[0] + kpos, Bs + wbase);
    gld16(BT + bbase[1] + kpos, Bs + 2048 + wbase);
    __syncthreads();   // vmcnt(0) drain -> LDS tile ready for all waves

    bf16x8 af[4], bg[4];
#pragma unroll
    for (int s = 0; s < 4; ++s) {
      af[s] = *(const bf16x8*)(As + aoffr + s * 512);
      bg[s] = *(const bf16x8*)(Bs + boffr + s * 512);
    }
#pragma unroll
    for (int i = 0; i < 4; ++i)
#pragma unroll
      for (int j = 0; j < 4; ++j)
        acc[i][j] = __builtin_amdgcn_mfma_f32_16x16x32_bf16(af[i], bg[j], acc[i][j], 0, 0, 0);
    __syncthreads();   // protect LDS from next iteration's overwrite
  }

  // raw bf16 partial store (squash + bias handled in tail)
  unsigned short* P = Pp + kid * 8388608;
  const int r4 = q << 2;
#pragma unroll
  for (int j = 0; j < 4; ++j) {
    int col = n0 + wn * 64 + j * 16 + rl;
#pragma unroll
    for (int i = 0; i < 4; ++i) {
      int mrow = m0 + wm * 64 + i * 16 + r4;
#pragma unroll
      for (int e = 0; e < 4; ++e)
        P[(size_t)(mrow + e) * 256 + col] = f2bf(acc[i][j][e]);
    }
  }
}

// --- K3: merge partials + primary squash + seg caps + length + recon -------
__global__ __launch_bounds__(128) void tail_k2(
    const unsigned short* __restrict__ Pp, const float* __restrict__ y,
    const float* __restrict__ bp, const float* __restrict__ cbp,
    const float* __restrict__ Ws, const float* __restrict__ bs,
    const float* __restrict__ cbs,
    const float* __restrict__ Wr1, const float* __restrict__ br1,
    const float* __restrict__ Wr2, const float* __restrict__ br2,
    const float* __restrict__ Wr3, const float* __restrict__ br3,
    float* __restrict__ out) {
  __shared__ float ccl[256];
  __shared__ float sbl[16];
  __shared__ float Wsl[128];
  __shared__ float W1l[1024];
  __shared__ float b1l[64];
  __shared__ float W2l[8192];
  __shared__ float b2l[128];
  __shared__ float W3l[128];

  const int tid = threadIdx.x;
  for (int i = tid; i < 256; i += 128) ccl[i] = bp[i] * (1.f / 32.f) + cbp[i];
  if (tid < 16) sbl[tid] = 32.f * bs[tid] + cbs[tid];
  if (tid < 128) { Wsl[tid] = Ws[tid]; b2l[tid] = br2[tid]; W3l[tid] = Wr3[tid]; }
  if (tid < 64) b1l[tid] = br1[tid];
  for (int i = tid; i < 1024; i += 128) W1l[i] = Wr1[i];
  for (int i = tid; i < 8192; i += 128) W2l[i] = Wr2[i];
  __syncthreads();

  const int m = blockIdx.x * 128 + tid;
  const us8* pr0 = (const us8*)(Pp + (size_t)m * 256);
  const us8* pr1 = (const us8*)(Pp + 8388608 + (size_t)m * 256);

  float P8[8] = {0.f, 0.f, 0.f, 0.f, 0.f, 0.f, 0.f, 0.f};
#pragma unroll 4
  for (int i = 0; i < 32; ++i) {
    us8 a = pr0[i], b = pr1[i];
    float v[8];
    float sq = 0.f;
#pragma unroll
    for (int c = 0; c < 8; ++c) {
      v[c] = (bf2f(a[c]) + bf2f(b[c])) * (1.f / 32.f) + ccl[i * 8 + c];
      sq += v[c] * v[c];
    }
    float scale = sq / ((1.f + sq) * sqrtf(sq + 1e-9f));
#pragma unroll
    for (int c = 0; c < 8; ++c) P8[c] += v[c] * scale;
  }

  // seg preact + squash + length
  float pre[16];
  float sq2 = 0.f;
#pragma unroll
  for (int a = 0; a < 16; ++a) {
    float s = sbl[a];
#pragma unroll
    for (int c = 0; c < 8; ++c) s += P8[c] * Wsl[a * 8 + c];
    pre[a] = s;
    sq2 += s * s;
  }
  float sc2 = sq2 / ((1.f + sq2) * sqrtf(sq2 + 1e-9f));
  out[m] = sqrtf(sq2 * sc2 * sc2 + 1e-9f);

  const float f = sc2 * y[m];
  float r1v[64];
#pragma unroll
  for (int j = 0; j < 64; ++j) {
    float s = b1l[j];
#pragma unroll
    for (int a = 0; a < 16; ++a) s += pre[a] * f * W1l[j * 16 + a];
    r1v[j] = fmaxf(s, 0.f);
  }
  float acc2 = br3[0];
  for (int k = 0; k < 128; ++k) {
    float s = b2l[k];
    const float4* wrow = (const float4*)(W2l + k * 64);
#pragma unroll
    for (int jj = 0; jj < 16; ++jj) {
      float4 wv = wrow[jj];
      s += r1v[jj * 4 + 0] * wv.x + r1v[jj * 4 + 1] * wv.y +
           r1v[jj * 4 + 2] * wv.z + r1v[jj * 4 + 3] * wv.w;
    }
    acc2 += fmaxf(s, 0.f) * W3l[k];
  }
  out[32768 + m] = 1.f / (1.f + expf(-acc2));
}

// ---------------------------------------------------------------------------
extern "C" void kernel_launch(void* const* d_in, const int* in_sizes, int n_in,
                              void* d_out, int out_size, void* d_ws, size_t ws_size,
                              hipStream_t stream) {
  const float* x   = (const float*)d_in[0];
  const float* y   = (const float*)d_in[1];
  const float* W1  = (const float*)d_in[2];
  const float* b1  = (const float*)d_in[3];
  const float* Wp  = (const float*)d_in[4];
  const float* bp  = (const float*)d_in[5];
  const float* cbp = (const float*)d_in[6];
  const float* Ws  = (const float*)d_in[7];
  const float* bs  = (const float*)d_in[8];
  const float* cbs = (const float*)d_in[9];
  const float* Wr1 = (const float*)d_in[10];
  const float* br1 = (const float*)d_in[11];
  const float* Wr2 = (const float*)d_in[12];
  const float* br2 = (const float*)d_in[13];
  const float* Wr3 = (const float*)d_in[14];
  const float* br3 = (const float*)d_in[15];
  float* out = (float*)d_out;

  char* ws = (char*)d_ws;
  unsigned short* Apad = (unsigned short*)ws;
  unsigned short* BT   = (unsigned short*)(ws + BT_OFF);
  unsigned short* Pp   = (unsigned short*)(ws + PP_OFF);

  hipMemsetAsync(Apad, 0, APAD_BYTES, stream);   // zero halo (and interior)
  hipLaunchKernelGGL(prep_w, dim3(6400), dim3(256), 0, stream, Wp, BT);
  hipLaunchKernelGGL(conv1_k, dim3(4096), dim3(256), 0, stream, x, W1, b1, Apad);
  hipLaunchKernelGGL(caps_conv2, dim3(1024), dim3(256), 0, stream, Apad, BT, Pp);
  hipLaunchKernelGGL(tail_k2, dim3(256), dim3(128), 0, stream,
                     Pp, y, bp, cbp, Ws, bs, cbs, Wr1, br1, Wr2, br2, Wr3, br3, out);
}

// Round 3
// 205.540 us; speedup vs baseline: 1.3744x; 1.0836x over previous
//
#include <hip/hip_runtime.h>
#include <hip/hip_bf16.h>

typedef __attribute__((ext_vector_type(8))) unsigned short us8;
typedef __attribute__((ext_vector_type(8))) __bf16 bf16x8;
typedef __attribute__((ext_vector_type(4))) float f32x4;

__device__ __forceinline__ unsigned short f2bf(float f) {
  unsigned int u = __float_as_uint(f);
  u += 0x7FFFu + ((u >> 16) & 1u);   // round-to-nearest-even
  return (unsigned short)(u >> 16);
}
__device__ __forceinline__ float bf2f(unsigned short u) {
  return __uint_as_float(((unsigned int)u) << 16);
}

// direct global->LDS DMA, 16B per lane (dest = wave-uniform base + lane*16)
__device__ __forceinline__ void gld16(const unsigned short* g, unsigned short* l) {
  __builtin_amdgcn_global_load_lds(reinterpret_cast<const unsigned int*>(g),
                                   reinterpret_cast<unsigned int*>(l), 16, 0, 0);
}

// ---------------------------------------------------------------------------
// ws layout (bytes)
//   Apad : [2][132][132][256] bf16  (conv1 out, zero halo of 2) = 17,842,176
//   BT   : [256][6400] bf16  (Wp transposed to [n][k], k=(dh*5+dw)*256+c)
//   Pp   : 2 x [32768][256] bf16 partials (split-K halves) = 33,554,432
// ---------------------------------------------------------------------------
#define APAD_BYTES 17842176
#define BT_OFF     17842176
#define PP_OFF     21118976

// --- K-1: zero only the halo strips of Apad (interior fully overwritten) ---
__global__ __launch_bounds__(256) void halo_zero(unsigned short* __restrict__ Apad) {
  int idx = blockIdx.x * 256 + threadIdx.x;   // 2*17424*32 = 1,115,136
  int t8 = idx & 31;
  int pix = idx >> 5;                          // 0..34847 (b*17424 + h*132 + w)
  int hw = pix % 17424;
  int h = hw / 132, w = hw - h * 132;
  if (h < 2 || h >= 130 || w < 2 || w >= 130) {
    us8 z = {0, 0, 0, 0, 0, 0, 0, 0};
    *(us8*)(Apad + (size_t)pix * 256 + t8 * 8) = z;
  }
}

// --- K0: weight prep via LDS transpose: BT[n][k]=bf16(Wp[n][c][dhw]) -------
__global__ __launch_bounds__(256) void prep_w(const float* __restrict__ Wp,
                                              unsigned short* __restrict__ BT) {
  __shared__ float w[6400];
  const int n = blockIdx.x;
  const float* src = Wp + n * 6400;
  for (int i = threadIdx.x; i < 6400; i += 256) w[i] = src[i];
  __syncthreads();
  for (int k = threadIdx.x; k < 6400; k += 256) {
    int dhw = k >> 8, c = k & 255;
    BT[n * 6400 + k] = f2bf(w[c * 25 + dhw]);
  }
}

// --- K1: conv1 = relu(conv5x5(x, W1)+b1), write padded NHWC bf16 -----------
__global__ __launch_bounds__(256) void conv1_k(const float* __restrict__ x,
                                               const float* __restrict__ W1,
                                               const float* __restrict__ b1,
                                               unsigned short* __restrict__ Apad) {
  int t = threadIdx.x;
  int pxt = blockIdx.x >> 3;                 // 512 pixel tiles of 64
  int cq  = blockIdx.x & 7;                  // 8 channel quads of 32
  int px  = (pxt << 6) + (t & 63);           // same (b,h) across the tile
  int cg  = __builtin_amdgcn_readfirstlane(t >> 6);   // wave-uniform
  int co0 = (cq << 5) + (cg << 3);           // 8 channels per thread
  int b = px >> 14, hw = px & 16383;
  int h = hw >> 7, w = hw & 127;

  float patch[25];
#pragma unroll
  for (int dh = 0; dh < 5; ++dh)
#pragma unroll
    for (int dw = 0; dw < 5; ++dw) {
      int hh = h + dh - 2, ww = w + dw - 2;
      bool ok = (hh >= 0) & (hh < 128) & (ww >= 0) & (ww < 128);
      patch[dh * 5 + dw] = ok ? x[(b << 14) + hh * 128 + ww] : 0.f;
    }
  us8 o;
#pragma unroll
  for (int c = 0; c < 8; ++c) {
    float acc = b1[co0 + c];
#pragma unroll
    for (int i = 0; i < 25; ++i) acc += patch[i] * W1[(co0 + c) * 25 + i];
    o[c] = f2bf(fmaxf(acc, 0.f));
  }
  *(us8*)(Apad + (size_t)((b * 132 + h + 2) * 132 + (w + 2)) * 256 + co0) = o;
}

// --- K2: implicit-GEMM conv, split-K=2, double-buffered 2-phase pipeline ---
// M = 32768 pixels, N = 256, K = 6400 = 25 taps * 256 c
// tile 128x128, 4 waves of 64x64, BK=32; grid = 2 kid x 2 bn x 256 bm = 1024
// LDS linear [128][32] bf16 x2 buffers; XOR part-swizzle on (source, read).
// Loop (T3 minimal recipe): STAGE(next) -> compute(cur) -> vmcnt(0)+barrier.
__global__ __launch_bounds__(256) void caps_conv2(
    const unsigned short* __restrict__ A,   // Apad NHWC bf16
    const unsigned short* __restrict__ BT,  // [256][6400] bf16
    unsigned short* __restrict__ Pp)        // 2 x [32768][256] bf16 partials
{
  __shared__ __attribute__((aligned(16))) unsigned short As[2][4096];
  __shared__ __attribute__((aligned(16))) unsigned short Bs[2][4096];

  const int tid = threadIdx.x;
  const int bid = blockIdx.x;
  // bijective XCD-chunked swizzle (1024 % 8 == 0), bm-major logical order
  const int lid = (bid & 7) * 128 + (bid >> 3);
  const int bm = lid >> 2;
  const int bn = (lid >> 1) & 1;
  const int kid = lid & 1;
  const int m0 = bm << 7, n0 = bn << 7;

  // staging role: row srow (+64 for second half), swizzled 16B part
  const int srow = tid >> 2;                              // 0..63
  const int p8 = (((tid & 3) ^ ((tid >> 3) & 3)) << 3);   // XOR-swizzled part *8

  int abase[2], bbase[2];
#pragma unroll
  for (int qr = 0; qr < 2; ++qr) {
    int m = m0 + srow + qr * 64;
    int b = m >> 14, hw = m & 16383;
    int h = hw >> 7, w = hw & 127;
    abase[qr] = ((b * 132 + h) * 132 + w) * 256 + p8;
    bbase[qr] = (n0 + srow + qr * 64) * 6400 + p8;
  }
  const int wbase = __builtin_amdgcn_readfirstlane((tid >> 6) << 9);  // wave*512

  const int lane = tid & 63;
  const int wid = tid >> 6;
  const int wm = wid >> 1, wn = wid & 1;
  const int rl = lane & 15, q = lane >> 4;
  const int qs = ((q ^ ((rl >> 1) & 3)) << 3);            // swizzled read part *8
  const int aoffr = (wm * 64 + rl) * 32 + qs;
  const int boffr = (wn * 64 + rl) * 32 + qs;

  f32x4 acc[4][4] = {};
  const int t0 = kid * 100;

  auto STAGE = [&](int buf, int t) {
    const int dhw = t >> 3;
    const int coff = (t & 7) << 5;
    const int dh = dhw / 5, dw = dhw - dh * 5;
    const int aoff = ((dh * 132 + dw) << 8) + coff;
    const int kpos = t << 5;
    gld16(A + abase[0] + aoff, &As[buf][wbase]);
    gld16(A + abase[1] + aoff, &As[buf][2048 + wbase]);
    gld16(BT + bbase[0] + kpos, &Bs[buf][wbase]);
    gld16(BT + bbase[1] + kpos, &Bs[buf][2048 + wbase]);
  };
  auto COMPUTE = [&](int buf) {
    bf16x8 af[4], bg[4];
#pragma unroll
    for (int s = 0; s < 4; ++s) {
      af[s] = *(const bf16x8*)(&As[buf][aoffr + s * 512]);
      bg[s] = *(const bf16x8*)(&Bs[buf][boffr + s * 512]);
    }
#pragma unroll
    for (int i = 0; i < 4; ++i)
#pragma unroll
      for (int j = 0; j < 4; ++j)
        acc[i][j] = __builtin_amdgcn_mfma_f32_16x16x32_bf16(af[i], bg[j], acc[i][j], 0, 0, 0);
  };

  STAGE(0, t0);
  asm volatile("s_waitcnt vmcnt(0)" ::: "memory");
  __builtin_amdgcn_s_barrier();
  int cur = 0;
  for (int i = 1; i < 100; ++i) {
    STAGE(cur ^ 1, t0 + i);          // issue next tile's loads first
    COMPUTE(cur);                    // hide load latency under ds_read+MFMA
    asm volatile("s_waitcnt vmcnt(0)" ::: "memory");
    __builtin_amdgcn_s_barrier();    // one barrier per K-step
    cur ^= 1;
  }
  COMPUTE(cur);

  // raw bf16 partial store (squash + bias handled in tail)
  unsigned short* P = Pp + kid * 8388608;
  const int r4 = q << 2;
#pragma unroll
  for (int j = 0; j < 4; ++j) {
    int col = n0 + wn * 64 + j * 16 + rl;
#pragma unroll
    for (int i = 0; i < 4; ++i) {
      int mrow = m0 + wm * 64 + i * 16 + r4;
#pragma unroll
      for (int e = 0; e < 4; ++e)
        P[(size_t)(mrow + e) * 256 + col] = f2bf(acc[i][j][e]);
    }
  }
}

// --- K3: merge partials + primary squash + seg caps + length + recon -------
__global__ __launch_bounds__(128) void tail_k2(
    const unsigned short* __restrict__ Pp, const float* __restrict__ y,
    const float* __restrict__ bp, const float* __restrict__ cbp,
    const float* __restrict__ Ws, const float* __restrict__ bs,
    const float* __restrict__ cbs,
    const float* __restrict__ Wr1, const float* __restrict__ br1,
    const float* __restrict__ Wr2, const float* __restrict__ br2,
    const float* __restrict__ Wr3, const float* __restrict__ br3,
    float* __restrict__ out) {
  __shared__ float ccl[256];
  __shared__ float sbl[16];
  __shared__ float Wsl[128];
  __shared__ float W1l[1024];
  __shared__ float b1l[64];
  __shared__ float W2l[8192];
  __shared__ float b2l[128];
  __shared__ float W3l[128];

  const int tid = threadIdx.x;
  for (int i = tid; i < 256; i += 128) ccl[i] = bp[i] * (1.f / 32.f) + cbp[i];
  if (tid < 16) sbl[tid] = 32.f * bs[tid] + cbs[tid];
  if (tid < 128) { Wsl[tid] = Ws[tid]; b2l[tid] = br2[tid]; W3l[tid] = Wr3[tid]; }
  if (tid < 64) b1l[tid] = br1[tid];
  for (int i = tid; i < 1024; i += 128) W1l[i] = Wr1[i];
  for (int i = tid; i < 8192; i += 128) W2l[i] = Wr2[i];
  __syncthreads();

  const int m = blockIdx.x * 128 + tid;
  const us8* pr0 = (const us8*)(Pp + (size_t)m * 256);
  const us8* pr1 = (const us8*)(Pp + 8388608 + (size_t)m * 256);

  float P8[8] = {0.f, 0.f, 0.f, 0.f, 0.f, 0.f, 0.f, 0.f};
#pragma unroll 4
  for (int i = 0; i < 32; ++i) {
    us8 a = pr0[i], b = pr1[i];
    float v[8];
    float sq = 0.f;
#pragma unroll
    for (int c = 0; c < 8; ++c) {
      v[c] = (bf2f(a[c]) + bf2f(b[c])) * (1.f / 32.f) + ccl[i * 8 + c];
      sq += v[c] * v[c];
    }
    float scale = sq / ((1.f + sq) * sqrtf(sq + 1e-9f));
#pragma unroll
    for (int c = 0; c < 8; ++c) P8[c] += v[c] * scale;
  }

  // seg preact + squash + length
  float pre[16];
  float sq2 = 0.f;
#pragma unroll
  for (int a = 0; a < 16; ++a) {
    float s = sbl[a];
#pragma unroll
    for (int c = 0; c < 8; ++c) s += P8[c] * Wsl[a * 8 + c];
    pre[a] = s;
    sq2 += s * s;
  }
  float sc2 = sq2 / ((1.f + sq2) * sqrtf(sq2 + 1e-9f));
  out[m] = sqrtf(sq2 * sc2 * sc2 + 1e-9f);

  const float f = sc2 * y[m];
  float r1v[64];
#pragma unroll
  for (int j = 0; j < 64; ++j) {
    float s = b1l[j];
#pragma unroll
    for (int a = 0; a < 16; ++a) s += pre[a] * f * W1l[j * 16 + a];
    r1v[j] = fmaxf(s, 0.f);
  }
  float acc2 = br3[0];
  for (int k = 0; k < 128; ++k) {
    float s = b2l[k];
    const float4* wrow = (const float4*)(W2l + k * 64);
#pragma unroll
    for (int jj = 0; jj < 16; ++jj) {
      float4 wv = wrow[jj];
      s += r1v[jj * 4 + 0] * wv.x + r1v[jj * 4 + 1] * wv.y +
           r1v[jj * 4 + 2] * wv.z + r1v[jj * 4 + 3] * wv.w;
    }
    acc2 += fmaxf(s, 0.f) * W3l[k];
  }
  out[32768 + m] = 1.f / (1.f + expf(-acc2));
}

// ---------------------------------------------------------------------------
extern "C" void kernel_launch(void* const* d_in, const int* in_sizes, int n_in,
                              void* d_out, int out_size, void* d_ws, size_t ws_size,
                              hipStream_t stream) {
  const float* x   = (const float*)d_in[0];
  const float* y   = (const float*)d_in[1];
  const float* W1  = (const float*)d_in[2];
  const float* b1  = (const float*)d_in[3];
  const float* Wp  = (const float*)d_in[4];
  const float* bp  = (const float*)d_in[5];
  const float* cbp = (const float*)d_in[6];
  const float* Ws  = (const float*)d_in[7];
  const float* bs  = (const float*)d_in[8];
  const float* cbs = (const float*)d_in[9];
  const float* Wr1 = (const float*)d_in[10];
  const float* br1 = (const float*)d_in[11];
  const float* Wr2 = (const float*)d_in[12];
  const float* br2 = (const float*)d_in[13];
  const float* Wr3 = (const float*)d_in[14];
  const float* br3 = (const float*)d_in[15];
  float* out = (float*)d_out;

  char* ws = (char*)d_ws;
  unsigned short* Apad = (unsigned short*)ws;
  unsigned short* BT   = (unsigned short*)(ws + BT_OFF);
  unsigned short* Pp   = (unsigned short*)(ws + PP_OFF);

  hipLaunchKernelGGL(halo_zero, dim3(4356), dim3(256), 0, stream, Apad);
  hipLaunchKernelGGL(prep_w, dim3(256), dim3(256), 0, stream, Wp, BT);
  hipLaunchKernelGGL(conv1_k, dim3(4096), dim3(256), 0, stream, x, W1, b1, Apad);
  hipLaunchKernelGGL(caps_conv2, dim3(1024), dim3(256), 0, stream, Apad, BT, Pp);
  hipLaunchKernelGGL(tail_k2, dim3(256), dim3(128), 0, stream,
                     Pp, y, bp, cbp, Ws, bs, cbs, Wr1, br1, Wr2, br2, Wr3, br3, out);
}

// Round 4
// 187.862 us; speedup vs baseline: 1.5037x; 1.0941x over previous
//
#include <hip/hip_runtime.h>
#include <hip/hip_bf16.h>

typedef __attribute__((ext_vector_type(8))) unsigned short us8;
typedef __attribute__((ext_vector_type(8))) __bf16 bf16x8;
typedef __attribute__((ext_vector_type(4))) float f32x4;

__device__ __forceinline__ unsigned short f2bf(float f) {
  unsigned int u = __float_as_uint(f);
  u += 0x7FFFu + ((u >> 16) & 1u);   // round-to-nearest-even
  return (unsigned short)(u >> 16);
}
__device__ __forceinline__ float bf2f(unsigned short u) {
  return __uint_as_float(((unsigned int)u) << 16);
}

// direct global->LDS DMA, 16B per lane (dest = wave-uniform base + lane*16)
__device__ __forceinline__ void gld16(const unsigned short* g, unsigned short* l) {
  __builtin_amdgcn_global_load_lds(reinterpret_cast<const unsigned int*>(g),
                                   reinterpret_cast<unsigned int*>(l), 16, 0, 0);
}

// ---------------------------------------------------------------------------
// ws layout (bytes)
//   Apad : [2][132][132][256] bf16  (conv1 out, zero halo of 2) = 17,842,176
//   BT   : [256][6400] bf16  (Wp transposed to [n][k], k=(dh*5+dw)*256+c)
//   Pp   : 2 x [32768][256] bf16 partials (split-K halves) = 33,554,432
// ---------------------------------------------------------------------------
#define APAD_BYTES 17842176
#define BT_OFF     17842176
#define PP_OFF     21118976

// --- K-1: zero only the halo strips of Apad (interior fully overwritten) ---
__global__ __launch_bounds__(256) void halo_zero(unsigned short* __restrict__ Apad) {
  int idx = blockIdx.x * 256 + threadIdx.x;   // 2*17424*32 = 1,115,136
  int t8 = idx & 31;
  int pix = idx >> 5;                          // 0..34847 (b*17424 + h*132 + w)
  int hw = pix % 17424;
  int h = hw / 132, w = hw - h * 132;
  if (h < 2 || h >= 130 || w < 2 || w >= 130) {
    us8 z = {0, 0, 0, 0, 0, 0, 0, 0};
    *(us8*)(Apad + (size_t)pix * 256 + t8 * 8) = z;
  }
}

// --- K0: weight prep via LDS transpose: BT[n][k]=bf16(Wp[n][c][dhw]) -------
__global__ __launch_bounds__(256) void prep_w(const float* __restrict__ Wp,
                                              unsigned short* __restrict__ BT) {
  __shared__ float w[6400];
  const int n = blockIdx.x;
  const float* src = Wp + n * 6400;
  for (int i = threadIdx.x; i < 6400; i += 256) w[i] = src[i];
  __syncthreads();
  for (int k = threadIdx.x; k < 6400; k += 256) {
    int dhw = k >> 8, c = k & 255;
    BT[n * 6400 + k] = f2bf(w[c * 25 + dhw]);
  }
}

// --- K1: conv1 = relu(conv5x5(x, W1)+b1), write padded NHWC bf16 -----------
__global__ __launch_bounds__(256) void conv1_k(const float* __restrict__ x,
                                               const float* __restrict__ W1,
                                               const float* __restrict__ b1,
                                               unsigned short* __restrict__ Apad) {
  int t = threadIdx.x;
  int pxt = blockIdx.x >> 3;                 // 512 pixel tiles of 64
  int cq  = blockIdx.x & 7;                  // 8 channel quads of 32
  int px  = (pxt << 6) + (t & 63);           // same (b,h) across the tile
  int cg  = __builtin_amdgcn_readfirstlane(t >> 6);   // wave-uniform
  int co0 = (cq << 5) + (cg << 3);           // 8 channels per thread
  int b = px >> 14, hw = px & 16383;
  int h = hw >> 7, w = hw & 127;

  float patch[25];
#pragma unroll
  for (int dh = 0; dh < 5; ++dh)
#pragma unroll
    for (int dw = 0; dw < 5; ++dw) {
      int hh = h + dh - 2, ww = w + dw - 2;
      bool ok = (hh >= 0) & (hh < 128) & (ww >= 0) & (ww < 128);
      patch[dh * 5 + dw] = ok ? x[(b << 14) + hh * 128 + ww] : 0.f;
    }
  us8 o;
#pragma unroll
  for (int c = 0; c < 8; ++c) {
    float acc = b1[co0 + c];
#pragma unroll
    for (int i = 0; i < 25; ++i) acc += patch[i] * W1[(co0 + c) * 25 + i];
    o[c] = f2bf(fmaxf(acc, 0.f));
  }
  *(us8*)(Apad + (size_t)((b * 132 + h + 2) * 132 + (w + 2)) * 256 + co0) = o;
}

// --- K2: implicit-GEMM conv, 256x256 tile, 8 waves, 8-phase-style pipeline -
// M = 32768 pixels, N = 256 (full), K = 6400 = 25 taps * 256 c, split-K = 2.
// LDS: ring of 4 k-unit slots (unit = BK=32), each A[256][32]+B[256][32] bf16
// with the proven conflict-free 64B-row XOR part-swizzle (source-preswizzled
// for global_load_lds, same XOR applied on ds_read). 2 phases per unit:
//   ph0: {read A-hi(u) | stage A(u+3)} vmcnt(6) bar [16 MFMA lo] bar
//   ph1: {read A-lo/B(u+1) | stage B(u+3)}        bar [16 MFMA hi] bar
// Counted vmcnt only (6 steady; 6/4/0 drain ladder in peeled tail).
#define STAGE_A(slot, ku) do { int dhw_=(ku)>>3, dh_=dhw_/5, dw_=dhw_-dh_*5;   \
    int ao_=((dh_*132+dw_)<<8)+(((ku)&7)<<5);                                  \
    gld16(Aap+abase0+ao_, &As[slot][sA]);                                      \
    gld16(Aap+abase1+ao_, &As[slot][sA+4096]); } while(0)
#define STAGE_B(slot, ku) do { int kp_=(ku)<<5;                                \
    gld16(BT+bbase0+kp_, &Bs[slot][sA]);                                       \
    gld16(BT+bbase1+kp_, &Bs[slot][sA+4096]); } while(0)
#define RDA(slot, s) (*(const bf16x8*)(&As[slot][areadbase + (s)*512]))
#define RDB(slot, j) (*(const bf16x8*)(&Bs[slot][breadbase + (j)*512]))
#define MFMA_Q(aset, bset, rb) do {                                            \
  _Pragma("unroll") for (int s_ = 0; s_ < 4; ++s_)                             \
  _Pragma("unroll") for (int j_ = 0; j_ < 4; ++j_)                             \
    acc[(rb)+s_][j_] = __builtin_amdgcn_mfma_f32_16x16x32_bf16(                \
        aset[s_], bset[j_], acc[(rb)+s_][j_], 0, 0, 0); } while(0)
#define BAR() __builtin_amdgcn_s_barrier()
#define VMC(n) asm volatile("s_waitcnt vmcnt(" #n ")" ::: "memory")

__global__ __launch_bounds__(512, 2) void caps_conv2(
    const unsigned short* __restrict__ Aap,  // Apad NHWC bf16
    const unsigned short* __restrict__ BT,   // [256][6400] bf16
    unsigned short* __restrict__ Pp)         // 2 x [32768][256] bf16 partials
{
  __shared__ __attribute__((aligned(16))) unsigned short As[4][8192];
  __shared__ __attribute__((aligned(16))) unsigned short Bs[4][8192];

  const int tid = threadIdx.x;
  const int bid = blockIdx.x;          // 256 blocks: kid x 128 bm-tiles
  const int kid = bid & 1;
  const int m0 = (bid >> 1) << 8;
  const int t0 = kid * 100;            // 100 k-units of 32 per split-K half
  const int wid = tid >> 6;
  const int l = tid & 63;

  // --- staging addresses (per-thread, source-preswizzled) ---
  const int swz = (l & 3) ^ ((l >> 2) & 3);
  int abase0, abase1, bbase0, bbase1;
  {
    int ra = wid * 16 + (l >> 2);               // 0..127
    int m = m0 + ra;
    int b = m >> 14, hw = m & 16383, h = hw >> 7, w = hw & 127;
    abase0 = ((b * 132 + h) * 132 + w) * 256 + swz * 8;
    m = m0 + ra + 128;
    b = m >> 14; hw = m & 16383; h = hw >> 7; w = hw & 127;
    abase1 = ((b * 132 + h) * 132 + w) * 256 + swz * 8;
    bbase0 = ra * 6400 + swz * 8;
    bbase1 = (ra + 128) * 6400 + swz * 8;
  }
  const int sA = wid * 512;            // LDS stage base (ushorts); +4096 rnd1

  // --- fragment-read addresses ---
  const int rl = l & 15, q = l >> 4;
  const int wm = wid >> 2, wn = wid & 3;       // 2x4 wave grid, tile 128x64
  const int areadbase = (wm * 128 + rl) * 32 + ((q ^ (rl & 3)) << 3);
  const int breadbase = (wn * 64 + rl) * 32 + ((q ^ (rl & 3)) << 3);

  f32x4 acc[8][4] = {};
  bf16x8 aL[2][4], aH[4], bB[2][4];

  // --- prologue: stage units 0,1,2; wait unit 0; preload its frags ---
  STAGE_A(0, t0 + 0); STAGE_B(0, t0 + 0);
  STAGE_A(1, t0 + 1); STAGE_B(1, t0 + 1);
  STAGE_A(2, t0 + 2); STAGE_B(2, t0 + 2);
  VMC(8); BAR();
#pragma unroll
  for (int s = 0; s < 4; ++s) aL[0][s] = RDA(0, s);
#pragma unroll
  for (int j = 0; j < 4; ++j) bB[0][j] = RDB(0, j);

  // --- main loop: units 0..95 (24 iters x 4 units x 2 phases) ---
  for (int it = 0; it < 24; ++it) {
    const int ub = t0 + it * 4;
#pragma unroll
    for (int sub = 0; sub < 4; ++sub) {
      const int par = sub & 1, nxt = par ^ 1;
      const int sU = sub, sU1 = (sub + 1) & 3, sS = (sub + 3) & 3;
      // phase 0
#pragma unroll
      for (int s = 0; s < 4; ++s) aH[s] = RDA(sU, 4 + s);
      STAGE_A(sS, ub + sub + 3);
      VMC(6); BAR();
      __builtin_amdgcn_s_setprio(1);
      MFMA_Q(aL[par], bB[par], 0);
      __builtin_amdgcn_s_setprio(0);
      BAR();
      // phase 1
#pragma unroll
      for (int s = 0; s < 4; ++s) aL[nxt][s] = RDA(sU1, s);
#pragma unroll
      for (int j = 0; j < 4; ++j) bB[nxt][j] = RDB(sU1, j);
      STAGE_B(sS, ub + sub + 3);
      BAR();
      __builtin_amdgcn_s_setprio(1);
      MFMA_Q(aH, bB[par], 4);
      __builtin_amdgcn_s_setprio(0);
      BAR();
    }
  }

  // --- peeled tail: units 96..99 with vmcnt drain ladder 6/4/0 ---
  // u=96 (par0, slot0; stage unit 99 -> slot3)
#pragma unroll
  for (int s = 0; s < 4; ++s) aH[s] = RDA(0, 4 + s);
  STAGE_A(3, t0 + 99);
  VMC(6); BAR();
  __builtin_amdgcn_s_setprio(1); MFMA_Q(aL[0], bB[0], 0);
  __builtin_amdgcn_s_setprio(0); BAR();
#pragma unroll
  for (int s = 0; s < 4; ++s) aL[1][s] = RDA(1, s);
#pragma unroll
  for (int j = 0; j < 4; ++j) bB[1][j] = RDB(1, j);
  STAGE_B(3, t0 + 99);
  BAR();
  __builtin_amdgcn_s_setprio(1); MFMA_Q(aH, bB[0], 4);
  __builtin_amdgcn_s_setprio(0); BAR();
  // u=97 (par1, slot1)
#pragma unroll
  for (int s = 0; s < 4; ++s) aH[s] = RDA(1, 4 + s);
  VMC(4); BAR();
  MFMA_Q(aL[1], bB[1], 0); BAR();
#pragma unroll
  for (int s = 0; s < 4; ++s) aL[0][s] = RDA(2, s);
#pragma unroll
  for (int j = 0; j < 4; ++j) bB[0][j] = RDB(2, j);
  BAR();
  MFMA_Q(aH, bB[1], 4); BAR();
  // u=98 (par0, slot2)
#pragma unroll
  for (int s = 0; s < 4; ++s) aH[s] = RDA(2, 4 + s);
  VMC(0); BAR();
  MFMA_Q(aL[0], bB[0], 0); BAR();
#pragma unroll
  for (int s = 0; s < 4; ++s) aL[1][s] = RDA(3, s);
#pragma unroll
  for (int j = 0; j < 4; ++j) bB[1][j] = RDB(3, j);
  BAR();
  MFMA_Q(aH, bB[0], 4); BAR();
  // u=99 (par1, slot3)
#pragma unroll
  for (int s = 0; s < 4; ++s) aH[s] = RDA(3, 4 + s);
  MFMA_Q(aL[1], bB[1], 0);
  MFMA_Q(aH, bB[1], 4);

  // --- epilogue: raw bf16 partial store (squash + bias in tail kernel) ---
  unsigned short* P = Pp + kid * 8388608;
#pragma unroll
  for (int s = 0; s < 8; ++s) {
#pragma unroll
    for (int j = 0; j < 4; ++j) {
      int col = wn * 64 + j * 16 + rl;
      int mrow = m0 + wm * 128 + s * 16 + (q << 2);
#pragma unroll
      for (int e = 0; e < 4; ++e)
        P[(size_t)(mrow + e) * 256 + col] = f2bf(acc[s][j][e]);
    }
  }
}

// --- K3: merge partials + primary squash + seg caps + length + recon -------
__global__ __launch_bounds__(128) void tail_k2(
    const unsigned short* __restrict__ Pp, const float* __restrict__ y,
    const float* __restrict__ bp, const float* __restrict__ cbp,
    const float* __restrict__ Ws, const float* __restrict__ bs,
    const float* __restrict__ cbs,
    const float* __restrict__ Wr1, const float* __restrict__ br1,
    const float* __restrict__ Wr2, const float* __restrict__ br2,
    const float* __restrict__ Wr3, const float* __restrict__ br3,
    float* __restrict__ out) {
  __shared__ float ccl[256];
  __shared__ float sbl[16];
  __shared__ float Wsl[128];
  __shared__ float W1l[1024];
  __shared__ float b1l[64];
  __shared__ float W2l[8192];
  __shared__ float b2l[128];
  __shared__ float W3l[128];

  const int tid = threadIdx.x;
  for (int i = tid; i < 256; i += 128) ccl[i] = bp[i] * (1.f / 32.f) + cbp[i];
  if (tid < 16) sbl[tid] = 32.f * bs[tid] + cbs[tid];
  if (tid < 128) { Wsl[tid] = Ws[tid]; b2l[tid] = br2[tid]; W3l[tid] = Wr3[tid]; }
  if (tid < 64) b1l[tid] = br1[tid];
  for (int i = tid; i < 1024; i += 128) W1l[i] = Wr1[i];
  for (int i = tid; i < 8192; i += 128) W2l[i] = Wr2[i];
  __syncthreads();

  const int m = blockIdx.x * 128 + tid;
  const us8* pr0 = (const us8*)(Pp + (size_t)m * 256);
  const us8* pr1 = (const us8*)(Pp + 8388608 + (size_t)m * 256);

  float P8[8] = {0.f, 0.f, 0.f, 0.f, 0.f, 0.f, 0.f, 0.f};
#pragma unroll 4
  for (int i = 0; i < 32; ++i) {
    us8 a = pr0[i], b = pr1[i];
    float v[8];
    float sq = 0.f;
#pragma unroll
    for (int c = 0; c < 8; ++c) {
      v[c] = (bf2f(a[c]) + bf2f(b[c])) * (1.f / 32.f) + ccl[i * 8 + c];
      sq += v[c] * v[c];
    }
    float scale = sq / ((1.f + sq) * sqrtf(sq + 1e-9f));
#pragma unroll
    for (int c = 0; c < 8; ++c) P8[c] += v[c] * scale;
  }

  // seg preact + squash + length
  float pre[16];
  float sq2 = 0.f;
#pragma unroll
  for (int a = 0; a < 16; ++a) {
    float s = sbl[a];
#pragma unroll
    for (int c = 0; c < 8; ++c) s += P8[c] * Wsl[a * 8 + c];
    pre[a] = s;
    sq2 += s * s;
  }
  float sc2 = sq2 / ((1.f + sq2) * sqrtf(sq2 + 1e-9f));
  out[m] = sqrtf(sq2 * sc2 * sc2 + 1e-9f);

  const float f = sc2 * y[m];
  float r1v[64];
#pragma unroll
  for (int j = 0; j < 64; ++j) {
    float s = b1l[j];
#pragma unroll
    for (int a = 0; a < 16; ++a) s += pre[a] * f * W1l[j * 16 + a];
    r1v[j] = fmaxf(s, 0.f);
  }
  float acc2 = br3[0];
  for (int k = 0; k < 128; ++k) {
    float s = b2l[k];
    const float4* wrow = (const float4*)(W2l + k * 64);
#pragma unroll
    for (int jj = 0; jj < 16; ++jj) {
      float4 wv = wrow[jj];
      s += r1v[jj * 4 + 0] * wv.x + r1v[jj * 4 + 1] * wv.y +
           r1v[jj * 4 + 2] * wv.z + r1v[jj * 4 + 3] * wv.w;
    }
    acc2 += fmaxf(s, 0.f) * W3l[k];
  }
  out[32768 + m] = 1.f / (1.f + expf(-acc2));
}

// ---------------------------------------------------------------------------
extern "C" void kernel_launch(void* const* d_in, const int* in_sizes, int n_in,
                              void* d_out, int out_size, void* d_ws, size_t ws_size,
                              hipStream_t stream) {
  const float* x   = (const float*)d_in[0];
  const float* y   = (const float*)d_in[1];
  const float* W1  = (const float*)d_in[2];
  const float* b1  = (const float*)d_in[3];
  const float* Wp  = (const float*)d_in[4];
  const float* bp  = (const float*)d_in[5];
  const float* cbp = (const float*)d_in[6];
  const float* Ws  = (const float*)d_in[7];
  const float* bs  = (const float*)d_in[8];
  const float* cbs = (const float*)d_in[9];
  const float* Wr1 = (const float*)d_in[10];
  const float* br1 = (const float*)d_in[11];
  const float* Wr2 = (const float*)d_in[12];
  const float* br2 = (const float*)d_in[13];
  const float* Wr3 = (const float*)d_in[14];
  const float* br3 = (const float*)d_in[15];
  float* out = (float*)d_out;

  char* ws = (char*)d_ws;
  unsigned short* Apad = (unsigned short*)ws;
  unsigned short* BT   = (unsigned short*)(ws + BT_OFF);
  unsigned short* Pp   = (unsigned short*)(ws + PP_OFF);

  hipLaunchKernelGGL(halo_zero, dim3(4356), dim3(256), 0, stream, Apad);
  hipLaunchKernelGGL(prep_w, dim3(256), dim3(256), 0, stream, Wp, BT);
  hipLaunchKernelGGL(conv1_k, dim3(4096), dim3(256), 0, stream, x, W1, b1, Apad);
  hipLaunchKernelGGL(caps_conv2, dim3(256), dim3(512), 0, stream, Apad, BT, Pp);
  hipLaunchKernelGGL(tail_k2, dim3(256), dim3(128), 0, stream,
                     Pp, y, bp, cbp, Ws, bs, cbs, Wr1, br1, Wr2, br2, Wr3, br3, out);
}

// Round 5
// 172.961 us; speedup vs baseline: 1.6332x; 1.0862x over previous
//
#include <hip/hip_runtime.h>
#include <hip/hip_bf16.h>

typedef __attribute__((ext_vector_type(8))) unsigned short us8;
typedef __attribute__((ext_vector_type(8))) __bf16 bf16x8;
typedef __attribute__((ext_vector_type(4))) float f32x4;

__device__ __forceinline__ unsigned short f2bf(float f) {
  unsigned int u = __float_as_uint(f);
  u += 0x7FFFu + ((u >> 16) & 1u);   // round-to-nearest-even
  return (unsigned short)(u >> 16);
}
__device__ __forceinline__ float bf2f(unsigned short u) {
  return __uint_as_float(((unsigned int)u) << 16);
}

// direct global->LDS DMA, 16B per lane (dest = wave-uniform base + lane*16)
__device__ __forceinline__ void gld16(const unsigned short* g, unsigned short* l) {
  __builtin_amdgcn_global_load_lds(reinterpret_cast<const unsigned int*>(g),
                                   reinterpret_cast<unsigned int*>(l), 16, 0, 0);
}

// ---------------------------------------------------------------------------
// ws layout (bytes)
//   Apad : [2][132][132][256] bf16  (conv1 out, zero halo of 2) = 17,842,176
//   BT   : [256][6400] bf16  (Wp transposed to [n][k], k=(dh*5+dw)*256+c)
//   Pp   : 2 x [32768][256] bf16 partials (split-K halves) = 33,554,432
// ---------------------------------------------------------------------------
#define APAD_BYTES 17842176
#define BT_OFF     17842176
#define PP_OFF     21118976

// --- K-1: zero only the halo strips of Apad (interior fully overwritten) ---
__global__ __launch_bounds__(256) void halo_zero(unsigned short* __restrict__ Apad) {
  int idx = blockIdx.x * 256 + threadIdx.x;   // 2*17424*32 = 1,115,136
  int t8 = idx & 31;
  int pix = idx >> 5;                          // 0..34847 (b*17424 + h*132 + w)
  int hw = pix % 17424;
  int h = hw / 132, w = hw - h * 132;
  if (h < 2 || h >= 130 || w < 2 || w >= 130) {
    us8 z = {0, 0, 0, 0, 0, 0, 0, 0};
    *(us8*)(Apad + (size_t)pix * 256 + t8 * 8) = z;
  }
}

// --- K0: weight prep via LDS transpose: BT[n][k]=bf16(Wp[n][c][dhw]) -------
__global__ __launch_bounds__(256) void prep_w(const float* __restrict__ Wp,
                                              unsigned short* __restrict__ BT) {
  __shared__ float w[6400];
  const int n = blockIdx.x;
  const float* src = Wp + n * 6400;
  for (int i = threadIdx.x; i < 6400; i += 256) w[i] = src[i];
  __syncthreads();
  for (int k = threadIdx.x; k < 6400; k += 256) {
    int dhw = k >> 8, c = k & 255;
    BT[n * 6400 + k] = f2bf(w[c * 25 + dhw]);
  }
}

// --- K1: conv1 = relu(conv5x5(x, W1)+b1), write padded NHWC bf16 -----------
__global__ __launch_bounds__(256) void conv1_k(const float* __restrict__ x,
                                               const float* __restrict__ W1,
                                               const float* __restrict__ b1,
                                               unsigned short* __restrict__ Apad) {
  int t = threadIdx.x;
  int pxt = blockIdx.x >> 3;                 // 512 pixel tiles of 64
  int cq  = blockIdx.x & 7;                  // 8 channel quads of 32
  int px  = (pxt << 6) + (t & 63);           // same (b,h) across the tile
  int cg  = __builtin_amdgcn_readfirstlane(t >> 6);   // wave-uniform
  int co0 = (cq << 5) + (cg << 3);           // 8 channels per thread
  int b = px >> 14, hw = px & 16383;
  int h = hw >> 7, w = hw & 127;

  float patch[25];
#pragma unroll
  for (int dh = 0; dh < 5; ++dh)
#pragma unroll
    for (int dw = 0; dw < 5; ++dw) {
      int hh = h + dh - 2, ww = w + dw - 2;
      bool ok = (hh >= 0) & (hh < 128) & (ww >= 0) & (ww < 128);
      patch[dh * 5 + dw] = ok ? x[(b << 14) + hh * 128 + ww] : 0.f;
    }
  us8 o;
#pragma unroll
  for (int c = 0; c < 8; ++c) {
    float acc = b1[co0 + c];
#pragma unroll
    for (int i = 0; i < 25; ++i) acc += patch[i] * W1[(co0 + c) * 25 + i];
    o[c] = f2bf(fmaxf(acc, 0.f));
  }
  *(us8*)(Apad + (size_t)((b * 132 + h + 2) * 132 + (w + 2)) * 256 + co0) = o;
}

// --- K2: implicit-GEMM conv, 256x256 tile, 8 waves, 8-phase-style pipeline -
// M = 32768 pixels, N = 256 (full), K = 6400 = 25 taps * 256 c, split-K = 2.
// LDS: ring of 4 k-unit slots (unit = BK=32), each A[256][32]+B[256][32] bf16.
// Conflict-free swizzle pair (rounds 2/3-proven): stage source part
// (l&3)^((l>>3)&3), read part q^((rl>>1)&3)  -> 2-way max (free, m136).
// 2 phases per unit, counted vmcnt only (6 steady; 6/4/0 tail ladder).
#define STAGE_A(slot, ku) do { int dhw_=(ku)>>3, dh_=dhw_/5, dw_=dhw_-dh_*5;   \
    int ao_=((dh_*132+dw_)<<8)+(((ku)&7)<<5);                                  \
    gld16(Aap+abase0+ao_, &As[slot][sA]);                                      \
    gld16(Aap+abase1+ao_, &As[slot][sA+4096]); } while(0)
#define STAGE_B(slot, ku) do { int kp_=(ku)<<5;                                \
    gld16(BT+bbase0+kp_, &Bs[slot][sA]);                                       \
    gld16(BT+bbase1+kp_, &Bs[slot][sA+4096]); } while(0)
#define RDA(slot, s) (*(const bf16x8*)(&As[slot][areadbase + (s)*512]))
#define RDB(slot, j) (*(const bf16x8*)(&Bs[slot][breadbase + (j)*512]))
#define MFMA_Q(aset, bset, rb) do {                                            \
  _Pragma("unroll") for (int s_ = 0; s_ < 4; ++s_)                             \
  _Pragma("unroll") for (int j_ = 0; j_ < 4; ++j_)                             \
    acc[(rb)+s_][j_] = __builtin_amdgcn_mfma_f32_16x16x32_bf16(                \
        aset[s_], bset[j_], acc[(rb)+s_][j_], 0, 0, 0); } while(0)
#define BAR() __builtin_amdgcn_s_barrier()
#define VMC(n) asm volatile("s_waitcnt vmcnt(" #n ")" ::: "memory")

__global__ __launch_bounds__(512, 2) void caps_conv2(
    const unsigned short* __restrict__ Aap,  // Apad NHWC bf16
    const unsigned short* __restrict__ BT,   // [256][6400] bf16
    unsigned short* __restrict__ Pp)         // 2 x [32768][256] bf16 partials
{
  __shared__ __attribute__((aligned(16))) unsigned short As[4][8192];
  __shared__ __attribute__((aligned(16))) unsigned short Bs[4][8192];

  const int tid = threadIdx.x;
  const int bid = blockIdx.x;          // 256 blocks
  // bijective XCD-chunked swizzle (256 % 8 == 0): XCD c gets lids
  // [c*32,(c+1)*32) = 16 contiguous bm-tiles x both split-K halves
  // -> per-XCD A window ~2.4 MB + B 3.3 MB (L2-resident).
  const int lid = (bid & 7) * 32 + (bid >> 3);
  const int kid = lid & 1;
  const int m0 = (lid >> 1) << 8;
  const int t0 = kid * 100;            // 100 k-units of 32 per split-K half
  const int wid = tid >> 6;
  const int l = tid & 63;

  // --- staging addresses (per-thread, source-preswizzled) ---
  const int swz = (l & 3) ^ ((l >> 3) & 3);   // matches read part q^((row>>1)&3)
  int abase0, abase1, bbase0, bbase1;
  {
    int ra = wid * 16 + (l >> 2);               // 0..127
    int m = m0 + ra;
    int b = m >> 14, hw = m & 16383, h = hw >> 7, w = hw & 127;
    abase0 = ((b * 132 + h) * 132 + w) * 256 + swz * 8;
    m = m0 + ra + 128;
    b = m >> 14; hw = m & 16383; h = hw >> 7; w = hw & 127;
    abase1 = ((b * 132 + h) * 132 + w) * 256 + swz * 8;
    bbase0 = ra * 6400 + swz * 8;
    bbase1 = (ra + 128) * 6400 + swz * 8;
  }
  const int sA = wid * 512;            // LDS stage base (ushorts); +4096 rnd1

  // --- fragment-read addresses ---
  const int rl = l & 15, q = l >> 4;
  const int wm = wid >> 2, wn = wid & 3;       // 2x4 wave grid, tile 128x64
  const int areadbase = (wm * 128 + rl) * 32 + ((q ^ ((rl >> 1) & 3)) << 3);
  const int breadbase = (wn * 64 + rl) * 32 + ((q ^ ((rl >> 1) & 3)) << 3);

  f32x4 acc[8][4] = {};
  bf16x8 aL[2][4], aH[4], bB[2][4];

  // --- prologue: stage units 0,1,2; wait unit 0; preload its frags ---
  STAGE_A(0, t0 + 0); STAGE_B(0, t0 + 0);
  STAGE_A(1, t0 + 1); STAGE_B(1, t0 + 1);
  STAGE_A(2, t0 + 2); STAGE_B(2, t0 + 2);
  VMC(8); BAR();
#pragma unroll
  for (int s = 0; s < 4; ++s) aL[0][s] = RDA(0, s);
#pragma unroll
  for (int j = 0; j < 4; ++j) bB[0][j] = RDB(0, j);

  // --- main loop: units 0..95 (24 iters x 4 units x 2 phases) ---
  for (int it = 0; it < 24; ++it) {
    const int ub = t0 + it * 4;
#pragma unroll
    for (int sub = 0; sub < 4; ++sub) {
      const int par = sub & 1, nxt = par ^ 1;
      const int sU = sub, sU1 = (sub + 1) & 3, sS = (sub + 3) & 3;
      // phase 0
#pragma unroll
      for (int s = 0; s < 4; ++s) aH[s] = RDA(sU, 4 + s);
      STAGE_A(sS, ub + sub + 3);
      VMC(6); BAR();
      __builtin_amdgcn_s_setprio(1);
      MFMA_Q(aL[par], bB[par], 0);
      __builtin_amdgcn_s_setprio(0);
      BAR();
      // phase 1
#pragma unroll
      for (int s = 0; s < 4; ++s) aL[nxt][s] = RDA(sU1, s);
#pragma unroll
      for (int j = 0; j < 4; ++j) bB[nxt][j] = RDB(sU1, j);
      STAGE_B(sS, ub + sub + 3);
      BAR();
      __builtin_amdgcn_s_setprio(1);
      MFMA_Q(aH, bB[par], 4);
      __builtin_amdgcn_s_setprio(0);
      BAR();
    }
  }

  // --- peeled tail: units 96..99 with vmcnt drain ladder 6/4/0 ---
  // u=96 (par0, slot0; stage unit 99 -> slot3)
#pragma unroll
  for (int s = 0; s < 4; ++s) aH[s] = RDA(0, 4 + s);
  STAGE_A(3, t0 + 99);
  VMC(6); BAR();
  __builtin_amdgcn_s_setprio(1); MFMA_Q(aL[0], bB[0], 0);
  __builtin_amdgcn_s_setprio(0); BAR();
#pragma unroll
  for (int s = 0; s < 4; ++s) aL[1][s] = RDA(1, s);
#pragma unroll
  for (int j = 0; j < 4; ++j) bB[1][j] = RDB(1, j);
  STAGE_B(3, t0 + 99);
  BAR();
  __builtin_amdgcn_s_setprio(1); MFMA_Q(aH, bB[0], 4);
  __builtin_amdgcn_s_setprio(0); BAR();
  // u=97 (par1, slot1)
#pragma unroll
  for (int s = 0; s < 4; ++s) aH[s] = RDA(1, 4 + s);
  VMC(4); BAR();
  MFMA_Q(aL[1], bB[1], 0); BAR();
#pragma unroll
  for (int s = 0; s < 4; ++s) aL[0][s] = RDA(2, s);
#pragma unroll
  for (int j = 0; j < 4; ++j) bB[0][j] = RDB(2, j);
  BAR();
  MFMA_Q(aH, bB[1], 4); BAR();
  // u=98 (par0, slot2)
#pragma unroll
  for (int s = 0; s < 4; ++s) aH[s] = RDA(2, 4 + s);
  VMC(0); BAR();
  MFMA_Q(aL[0], bB[0], 0); BAR();
#pragma unroll
  for (int s = 0; s < 4; ++s) aL[1][s] = RDA(3, s);
#pragma unroll
  for (int j = 0; j < 4; ++j) bB[1][j] = RDB(3, j);
  BAR();
  MFMA_Q(aH, bB[0], 4); BAR();
  // u=99 (par1, slot3)
#pragma unroll
  for (int s = 0; s < 4; ++s) aH[s] = RDA(3, 4 + s);
  MFMA_Q(aL[1], bB[1], 0);
  MFMA_Q(aH, bB[1], 4);

  // --- epilogue: raw bf16 partial store (squash + bias in tail kernel) ---
  unsigned short* P = Pp + kid * 8388608;
#pragma unroll
  for (int s = 0; s < 8; ++s) {
#pragma unroll
    for (int j = 0; j < 4; ++j) {
      int col = wn * 64 + j * 16 + rl;
      int mrow = m0 + wm * 128 + s * 16 + (q << 2);
#pragma unroll
      for (int e = 0; e < 4; ++e)
        P[(size_t)(mrow + e) * 256 + col] = f2bf(acc[s][j][e]);
    }
  }
}

// --- K3: merge partials + primary squash + seg caps + length + recon -------
__global__ __launch_bounds__(128) void tail_k2(
    const unsigned short* __restrict__ Pp, const float* __restrict__ y,
    const float* __restrict__ bp, const float* __restrict__ cbp,
    const float* __restrict__ Ws, const float* __restrict__ bs,
    const float* __restrict__ cbs,
    const float* __restrict__ Wr1, const float* __restrict__ br1,
    const float* __restrict__ Wr2, const float* __restrict__ br2,
    const float* __restrict__ Wr3, const float* __restrict__ br3,
    float* __restrict__ out) {
  __shared__ float ccl[256];
  __shared__ float sbl[16];
  __shared__ float Wsl[128];
  __shared__ float W1l[1024];
  __shared__ float b1l[64];
  __shared__ float W2l[8192];
  __shared__ float b2l[128];
  __shared__ float W3l[128];

  const int tid = threadIdx.x;
  for (int i = tid; i < 256; i += 128) ccl[i] = bp[i] * (1.f / 32.f) + cbp[i];
  if (tid < 16) sbl[tid] = 32.f * bs[tid] + cbs[tid];
  if (tid < 128) { Wsl[tid] = Ws[tid]; b2l[tid] = br2[tid]; W3l[tid] = Wr3[tid]; }
  if (tid < 64) b1l[tid] = br1[tid];
  for (int i = tid; i < 1024; i += 128) W1l[i] = Wr1[i];
  for (int i = tid; i < 8192; i += 128) W2l[i] = Wr2[i];
  __syncthreads();

  const int m = blockIdx.x * 128 + tid;
  const us8* pr0 = (const us8*)(Pp + (size_t)m * 256);
  const us8* pr1 = (const us8*)(Pp + 8388608 + (size_t)m * 256);

  float P8[8] = {0.f, 0.f, 0.f, 0.f, 0.f, 0.f, 0.f, 0.f};
#pragma unroll 4
  for (int i = 0; i < 32; ++i) {
    us8 a = pr0[i], b = pr1[i];
    float v[8];
    float sq = 0.f;
#pragma unroll
    for (int c = 0; c < 8; ++c) {
      v[c] = (bf2f(a[c]) + bf2f(b[c])) * (1.f / 32.f) + ccl[i * 8 + c];
      sq += v[c] * v[c];
    }
    float scale = sq / ((1.f + sq) * sqrtf(sq + 1e-9f));
#pragma unroll
    for (int c = 0; c < 8; ++c) P8[c] += v[c] * scale;
  }

  // seg preact + squash + length
  float pre[16];
  float sq2 = 0.f;
#pragma unroll
  for (int a = 0; a < 16; ++a) {
    float s = sbl[a];
#pragma unroll
    for (int c = 0; c < 8; ++c) s += P8[c] * Wsl[a * 8 + c];
    pre[a] = s;
    sq2 += s * s;
  }
  float sc2 = sq2 / ((1.f + sq2) * sqrtf(sq2 + 1e-9f));
  out[m] = sqrtf(sq2 * sc2 * sc2 + 1e-9f);

  const float f = sc2 * y[m];
  float r1v[64];
#pragma unroll
  for (int j = 0; j < 64; ++j) {
    float s = b1l[j];
#pragma unroll
    for (int a = 0; a < 16; ++a) s += pre[a] * f * W1l[j * 16 + a];
    r1v[j] = fmaxf(s, 0.f);
  }
  float acc2 = br3[0];
  for (int k = 0; k < 128; ++k) {
    float s = b2l[k];
    const float4* wrow = (const float4*)(W2l + k * 64);
#pragma unroll
    for (int jj = 0; jj < 16; ++jj) {
      float4 wv = wrow[jj];
      s += r1v[jj * 4 + 0] * wv.x + r1v[jj * 4 + 1] * wv.y +
           r1v[jj * 4 + 2] * wv.z + r1v[jj * 4 + 3] * wv.w;
    }
    acc2 += fmaxf(s, 0.f) * W3l[k];
  }
  out[32768 + m] = 1.f / (1.f + expf(-acc2));
}

// ---------------------------------------------------------------------------
extern "C" void kernel_launch(void* const* d_in, const int* in_sizes, int n_in,
                              void* d_out, int out_size, void* d_ws, size_t ws_size,
                              hipStream_t stream) {
  const float* x   = (const float*)d_in[0];
  const float* y   = (const float*)d_in[1];
  const float* W1  = (const float*)d_in[2];
  const float* b1  = (const float*)d_in[3];
  const float* Wp  = (const float*)d_in[4];
  const float* bp  = (const float*)d_in[5];
  const float* cbp = (const float*)d_in[6];
  const float* Ws  = (const float*)d_in[7];
  const float* bs  = (const float*)d_in[8];
  const float* cbs = (const float*)d_in[9];
  const float* Wr1 = (const float*)d_in[10];
  const float* br1 = (const float*)d_in[11];
  const float* Wr2 = (const float*)d_in[12];
  const float* br2 = (const float*)d_in[13];
  const float* Wr3 = (const float*)d_in[14];
  const float* br3 = (const float*)d_in[15];
  float* out = (float*)d_out;

  char* ws = (char*)d_ws;
  unsigned short* Apad = (unsigned short*)ws;
  unsigned short* BT   = (unsigned short*)(ws + BT_OFF);
  unsigned short* Pp   = (unsigned short*)(ws + PP_OFF);

  hipLaunchKernelGGL(halo_zero, dim3(4356), dim3(256), 0, stream, Apad);
  hipLaunchKernelGGL(prep_w, dim3(256), dim3(256), 0, stream, Wp, BT);
  hipLaunchKernelGGL(conv1_k, dim3(4096), dim3(256), 0, stream, x, W1, b1, Apad);
  hipLaunchKernelGGL(caps_conv2, dim3(256), dim3(512), 0, stream, Apad, BT, Pp);
  hipLaunchKernelGGL(tail_k2, dim3(256), dim3(128), 0, stream,
                     Pp, y, bp, cbp, Ws, bs, cbs, Wr1, br1, Wr2, br2, Wr3, br3, out);
}

// Round 6
// 162.728 us; speedup vs baseline: 1.7359x; 1.0629x over previous
//
#include <hip/hip_runtime.h>
#include <hip/hip_bf16.h>

typedef __attribute__((ext_vector_type(8))) unsigned short us8;
typedef __attribute__((ext_vector_type(8))) __bf16 bf16x8;
typedef __attribute__((ext_vector_type(4))) float f32x4;

__device__ __forceinline__ unsigned short f2bf(float f) {
  unsigned int u = __float_as_uint(f);
  u += 0x7FFFu + ((u >> 16) & 1u);   // round-to-nearest-even
  return (unsigned short)(u >> 16);
}
__device__ __forceinline__ float bf2f(unsigned short u) {
  return __uint_as_float(((unsigned int)u) << 16);
}

// direct global->LDS DMA, 16B per lane (dest = wave-uniform base + lane*16)
__device__ __forceinline__ void gld16(const unsigned short* g, unsigned short* l) {
  __builtin_amdgcn_global_load_lds(reinterpret_cast<const unsigned int*>(g),
                                   reinterpret_cast<unsigned int*>(l), 16, 0, 0);
}

// ---------------------------------------------------------------------------
// ws layout (bytes)
//   Apad : [2][132][132][256] bf16  (conv1 out, zero halo of 2) = 17,842,176
//   BT   : [256][6400] bf16  (Wp transposed to [n][k], k=(dh*5+dw)*256+c)
//   Pp   : 2 x [32768][256] bf16 partials (split-K halves) = 33,554,432
// ---------------------------------------------------------------------------
#define APAD_BYTES 17842176
#define BT_OFF     17842176
#define PP_OFF     21118976

// --- K0: fused weight prep (blocks 0..255) + halo zero (blocks 256..515) ---
__global__ __launch_bounds__(256) void prep_halo(const float* __restrict__ Wp,
                                                 unsigned short* __restrict__ BT,
                                                 unsigned short* __restrict__ Apad) {
  __shared__ float w[6400];
  const int bid = blockIdx.x, tid = threadIdx.x;
  if (bid < 256) {
    const float* src = Wp + bid * 6400;
    for (int i = tid; i < 6400; i += 256) w[i] = src[i];
    __syncthreads();
    for (int k = tid; k < 6400; k += 256) {
      int dhw = k >> 8, c = k & 255;
      BT[bid * 6400 + k] = f2bf(w[c * 25 + dhw]);
    }
  } else {
    // 2 images x 1040 halo pixels x 32 us8-chunks = 66,560 writes
    int idx = (bid - 256) * 256 + tid;
    int chunk = idx & 31;
    int pix = idx >> 5;                 // 0..2079
    int img = pix >= 1040;
    int p = pix - img * 1040;
    int h, w2;
    if (p < 528) {                      // rows {0,1,130,131} full width
      int rs = p / 132;
      h = (rs < 2) ? rs : rs + 128;
      w2 = p - rs * 132;
    } else {                            // rows 2..129, cols {0,1,130,131}
      int q = p - 528;
      h = 2 + (q >> 2);
      int cs = q & 3;
      w2 = (cs < 2) ? cs : cs + 128;
    }
    us8 z = {0, 0, 0, 0, 0, 0, 0, 0};
    *(us8*)(Apad + (size_t)(img * 17424 + h * 132 + w2) * 256 + chunk * 8) = z;
  }
}

// --- K1: conv1 = relu(conv5x5(x, W1)+b1), write padded NHWC bf16 -----------
__global__ __launch_bounds__(256) void conv1_k(const float* __restrict__ x,
                                               const float* __restrict__ W1,
                                               const float* __restrict__ b1,
                                               unsigned short* __restrict__ Apad) {
  int t = threadIdx.x;
  int pxt = blockIdx.x >> 3;                 // 512 pixel tiles of 64
  int cq  = blockIdx.x & 7;                  // 8 channel quads of 32
  int px  = (pxt << 6) + (t & 63);           // same (b,h) across the tile
  int cg  = __builtin_amdgcn_readfirstlane(t >> 6);   // wave-uniform
  int co0 = (cq << 5) + (cg << 3);           // 8 channels per thread
  int b = px >> 14, hw = px & 16383;
  int h = hw >> 7, w = hw & 127;

  float patch[25];
#pragma unroll
  for (int dh = 0; dh < 5; ++dh)
#pragma unroll
    for (int dw = 0; dw < 5; ++dw) {
      int hh = h + dh - 2, ww = w + dw - 2;
      bool ok = (hh >= 0) & (hh < 128) & (ww >= 0) & (ww < 128);
      patch[dh * 5 + dw] = ok ? x[(b << 14) + hh * 128 + ww] : 0.f;
    }
  us8 o;
#pragma unroll
  for (int c = 0; c < 8; ++c) {
    float acc = b1[co0 + c];
#pragma unroll
    for (int i = 0; i < 25; ++i) acc += patch[i] * W1[(co0 + c) * 25 + i];
    o[c] = f2bf(fmaxf(acc, 0.f));
  }
  *(us8*)(Apad + (size_t)((b * 132 + h + 2) * 132 + (w + 2)) * 256 + co0) = o;
}

// --- K2: implicit-GEMM conv, 256x256 tile, 8 waves, 2-phase/BK32 pipeline --
// Conflict-free swizzle pair: stage source part (l&3)^((l>>3)&3),
// read part q^((rl>>1)&3). Counted vmcnt only (6 steady; 6/4/0 tail ladder).
// Balanced reads: ph0 = {aH(u), bB(u+1) post-VMC}, ph1 = {aL(u+1)}.
#define STAGE_A(slot, ku) do { int dhw_=(ku)>>3, dh_=dhw_/5, dw_=dhw_-dh_*5;   \
    int ao_=((dh_*132+dw_)<<8)+(((ku)&7)<<5);                                  \
    gld16(Aap+abase0+ao_, &As[slot][sA]);                                      \
    gld16(Aap+abase1+ao_, &As[slot][sA+4096]); } while(0)
#define STAGE_B(slot, ku) do { int kp_=(ku)<<5;                                \
    gld16(BT+bbase0+kp_, &Bs[slot][sA]);                                       \
    gld16(BT+bbase1+kp_, &Bs[slot][sA+4096]); } while(0)
#define RDA(slot, s) (*(const bf16x8*)(&As[slot][areadbase + (s)*512]))
#define RDB(slot, j) (*(const bf16x8*)(&Bs[slot][breadbase + (j)*512]))
#define MFMA_Q(aset, bset, rb) do {                                            \
  _Pragma("unroll") for (int s_ = 0; s_ < 4; ++s_)                             \
  _Pragma("unroll") for (int j_ = 0; j_ < 4; ++j_)                             \
    acc[(rb)+s_][j_] = __builtin_amdgcn_mfma_f32_16x16x32_bf16(                \
        aset[s_], bset[j_], acc[(rb)+s_][j_], 0, 0, 0); } while(0)
#define BAR() __builtin_amdgcn_s_barrier()
#define VMC(n) asm volatile("s_waitcnt vmcnt(" #n ")" ::: "memory")

__global__ __launch_bounds__(512, 2) void caps_conv2(
    const unsigned short* __restrict__ Aap,  // Apad NHWC bf16
    const unsigned short* __restrict__ BT,   // [256][6400] bf16
    unsigned short* __restrict__ Pp)         // 2 x [32768][256] bf16 partials
{
  __shared__ __attribute__((aligned(16))) unsigned short As[4][8192];
  __shared__ __attribute__((aligned(16))) unsigned short Bs[4][8192];

  const int tid = threadIdx.x;
  const int bid = blockIdx.x;          // 256 blocks
  // bijective XCD-chunked swizzle: per-XCD window L2-resident
  const int lid = (bid & 7) * 32 + (bid >> 3);
  const int kid = lid & 1;
  const int m0 = (lid >> 1) << 8;
  const int t0 = kid * 100;            // 100 k-units of 32 per split-K half
  const int wid = tid >> 6;
  const int l = tid & 63;

  // --- staging addresses (per-thread, source-preswizzled) ---
  const int swz = (l & 3) ^ ((l >> 3) & 3);   // matches read part q^((row>>1)&3)
  int abase0, abase1, bbase0, bbase1;
  {
    int ra = wid * 16 + (l >> 2);               // 0..127
    int m = m0 + ra;
    int b = m >> 14, hw = m & 16383, h = hw >> 7, w = hw & 127;
    abase0 = ((b * 132 + h) * 132 + w) * 256 + swz * 8;
    m = m0 + ra + 128;
    b = m >> 14; hw = m & 16383; h = hw >> 7; w = hw & 127;
    abase1 = ((b * 132 + h) * 132 + w) * 256 + swz * 8;
    bbase0 = ra * 6400 + swz * 8;
    bbase1 = (ra + 128) * 6400 + swz * 8;
  }
  const int sA = wid * 512;            // LDS stage base (ushorts); +4096 rnd1

  // --- fragment-read addresses ---
  const int rl = l & 15, q = l >> 4;
  const int wm = wid >> 2, wn = wid & 3;       // 2x4 wave grid, tile 128x64
  const int areadbase = (wm * 128 + rl) * 32 + ((q ^ ((rl >> 1) & 3)) << 3);
  const int breadbase = (wn * 64 + rl) * 32 + ((q ^ ((rl >> 1) & 3)) << 3);

  f32x4 acc[8][4] = {};
  bf16x8 aL[2][4], aH[4], bB[2][4];

  // --- prologue: stage units 0,1,2; wait unit 0; preload its frags ---
  STAGE_A(0, t0 + 0); STAGE_B(0, t0 + 0);
  STAGE_A(1, t0 + 1); STAGE_B(1, t0 + 1);
  STAGE_A(2, t0 + 2); STAGE_B(2, t0 + 2);
  VMC(8); BAR();
#pragma unroll
  for (int s = 0; s < 4; ++s) aL[0][s] = RDA(0, s);
#pragma unroll
  for (int j = 0; j < 4; ++j) bB[0][j] = RDB(0, j);

  // --- main loop: units 0..95 (24 iters x 4 units x 2 phases) ---
  for (int it = 0; it < 24; ++it) {
    const int ub = t0 + it * 4;
#pragma unroll
    for (int sub = 0; sub < 4; ++sub) {
      const int par = sub & 1, nxt = par ^ 1;
      const int sU = sub, sU1 = (sub + 1) & 3, sS = (sub + 3) & 3;
      // phase 0: aH(u) reads + A-stage + VMC + bB(u+1) reads
#pragma unroll
      for (int s = 0; s < 4; ++s) aH[s] = RDA(sU, 4 + s);
      STAGE_A(sS, ub + sub + 3);
      VMC(6);
#pragma unroll
      for (int j = 0; j < 4; ++j) bB[nxt][j] = RDB(sU1, j);
      BAR();
      __builtin_amdgcn_s_setprio(1);
      MFMA_Q(aL[par], bB[par], 0);
      __builtin_amdgcn_s_setprio(0);
      BAR();
      // phase 1: aL(u+1) reads + B-stage
#pragma unroll
      for (int s = 0; s < 4; ++s) aL[nxt][s] = RDA(sU1, s);
      STAGE_B(sS, ub + sub + 3);
      BAR();
      __builtin_amdgcn_s_setprio(1);
      MFMA_Q(aH, bB[par], 4);
      __builtin_amdgcn_s_setprio(0);
      BAR();
    }
  }

  // --- peeled tail: units 96..99 with vmcnt drain ladder 6/4/0 ---
  // u=96 (par0, slot0; stage unit 99 -> slot3)
#pragma unroll
  for (int s = 0; s < 4; ++s) aH[s] = RDA(0, 4 + s);
  STAGE_A(3, t0 + 99);
  VMC(6);
#pragma unroll
  for (int j = 0; j < 4; ++j) bB[1][j] = RDB(1, j);
  BAR();
  __builtin_amdgcn_s_setprio(1); MFMA_Q(aL[0], bB[0], 0);
  __builtin_amdgcn_s_setprio(0); BAR();
#pragma unroll
  for (int s = 0; s < 4; ++s) aL[1][s] = RDA(1, s);
  STAGE_B(3, t0 + 99);
  BAR();
  __builtin_amdgcn_s_setprio(1); MFMA_Q(aH, bB[0], 4);
  __builtin_amdgcn_s_setprio(0); BAR();
  // u=97 (par1, slot1)
#pragma unroll
  for (int s = 0; s < 4; ++s) aH[s] = RDA(1, 4 + s);
  VMC(4);
#pragma unroll
  for (int j = 0; j < 4; ++j) bB[0][j] = RDB(2, j);
  BAR();
  MFMA_Q(aL[1], bB[1], 0); BAR();
#pragma unroll
  for (int s = 0; s < 4; ++s) aL[0][s] = RDA(2, s);
  BAR();
  MFMA_Q(aH, bB[1], 4); BAR();
  // u=98 (par0, slot2)
#pragma unroll
  for (int s = 0; s < 4; ++s) aH[s] = RDA(2, 4 + s);
  VMC(0);
#pragma unroll
  for (int j = 0; j < 4; ++j) bB[1][j] = RDB(3, j);
  BAR();
  MFMA_Q(aL[0], bB[0], 0); BAR();
#pragma unroll
  for (int s = 0; s < 4; ++s) aL[1][s] = RDA(3, s);
  BAR();
  MFMA_Q(aH, bB[0], 4); BAR();
  // u=99 (par1, slot3)
#pragma unroll
  for (int s = 0; s < 4; ++s) aH[s] = RDA(3, 4 + s);
  MFMA_Q(aL[1], bB[1], 0);
  MFMA_Q(aH, bB[1], 4);

  // --- epilogue: raw bf16 partial store (squash + bias in tail kernel) ---
  unsigned short* P = Pp + kid * 8388608;
#pragma unroll
  for (int s = 0; s < 8; ++s) {
#pragma unroll
    for (int j = 0; j < 4; ++j) {
      int col = wn * 64 + j * 16 + rl;
      int mrow = m0 + wm * 128 + s * 16 + (q << 2);
#pragma unroll
      for (int e = 0; e < 4; ++e)
        P[(size_t)(mrow + e) * 256 + col] = f2bf(acc[s][j][e]);
    }
  }
}

// --- K3: merge + squash + seg + recon, 2 threads/pixel, chains broken ------
__global__ __launch_bounds__(256) void tail_k3(
    const unsigned short* __restrict__ Pp, const float* __restrict__ y,
    const float* __restrict__ bp, const float* __restrict__ cbp,
    const float* __restrict__ Ws, const float* __restrict__ bs,
    const float* __restrict__ cbs,
    const float* __restrict__ Wr1, const float* __restrict__ br1,
    const float* __restrict__ Wr2, const float* __restrict__ br2,
    const float* __restrict__ Wr3, const float* __restrict__ br3,
    float* __restrict__ out) {
  __shared__ float ccl[256];
  __shared__ float sbl[16];
  __shared__ float Wsl[128];
  __shared__ float W1l[1024];
  __shared__ float b1l[64];
  __shared__ float W2l[8192];
  __shared__ float b2l[128];
  __shared__ float W3l[128];

  const int tid = threadIdx.x;
  ccl[tid] = bp[tid] * (1.f / 32.f) + cbp[tid];
  if (tid < 16) sbl[tid] = 32.f * bs[tid] + cbs[tid];
  if (tid < 128) { Wsl[tid] = Ws[tid]; b2l[tid] = br2[tid]; W3l[tid] = Wr3[tid]; }
  if (tid < 64) b1l[tid] = br1[tid];
  for (int i = tid; i < 1024; i += 256) W1l[i] = Wr1[i];
  for (int i = tid; i < 8192; i += 256) W2l[i] = Wr2[i];
  __syncthreads();

  const int m = blockIdx.x * 128 + (tid >> 1);   // 256 blocks x 128 pixels
  const int hf = tid & 1;                         // half: splits i/j/k loops

  // merge 16 of 32 primary capsules per half
  const us8* pr0 = (const us8*)(Pp + (size_t)m * 256) + hf * 16;
  const us8* pr1 = (const us8*)(Pp + 8388608 + (size_t)m * 256) + hf * 16;
  float P8[8] = {0.f, 0.f, 0.f, 0.f, 0.f, 0.f, 0.f, 0.f};
#pragma unroll 4
  for (int i = 0; i < 16; ++i) {
    us8 a = pr0[i], b = pr1[i];
    const int ci = (hf * 16 + i) * 8;
    float v[8];
#pragma unroll
    for (int c = 0; c < 8; ++c)
      v[c] = (bf2f(a[c]) + bf2f(b[c])) * (1.f / 32.f) + ccl[ci + c];
    float sqa = v[0]*v[0] + v[1]*v[1] + v[2]*v[2] + v[3]*v[3];
    float sqb = v[4]*v[4] + v[5]*v[5] + v[6]*v[6] + v[7]*v[7];
    float sq = sqa + sqb;
    float scale = sq / ((1.f + sq) * sqrtf(sq + 1e-9f));
#pragma unroll
    for (int c = 0; c < 8; ++c) P8[c] += v[c] * scale;
  }
#pragma unroll
  for (int c = 0; c < 8; ++c) P8[c] += __shfl_xor(P8[c], 1);

  // seg preact + squash + length (both halves duplicate: cheap)
  float pre[16];
  float sqx = 0.f, sqy = 0.f;
#pragma unroll
  for (int a = 0; a < 16; ++a) {
    float s0 = P8[0]*Wsl[a*8+0] + P8[1]*Wsl[a*8+1] + P8[2]*Wsl[a*8+2] + P8[3]*Wsl[a*8+3];
    float s1 = P8[4]*Wsl[a*8+4] + P8[5]*Wsl[a*8+5] + P8[6]*Wsl[a*8+6] + P8[7]*Wsl[a*8+7];
    float s = sbl[a] + s0 + s1;
    pre[a] = s;
    if (a & 1) sqy += s * s; else sqx += s * s;
  }
  float sq2 = sqx + sqy;
  float sc2 = sq2 / ((1.f + sq2) * sqrtf(sq2 + 1e-9f));
  if (hf == 0) out[m] = sqrtf(sq2 * sc2 * sc2 + 1e-9f);

  const float f = sc2 * y[m];
  // r1: each half computes 32 of 64 (j = hf*32 + jj)
  float r1o[32];
#pragma unroll
  for (int jj = 0; jj < 32; ++jj) {
    const float* wr = W1l + (hf * 32 + jj) * 16;
    float s0 = 0.f, s1 = 0.f;
#pragma unroll
    for (int a = 0; a < 8; ++a) { s0 += pre[a] * f * wr[a]; s1 += pre[a+8] * f * wr[a+8]; }
    r1o[jj] = fmaxf(b1l[hf * 32 + jj] + s0 + s1, 0.f);
  }
  // exchange: lo = r1[j<32], hi = r1[j>=32] for BOTH halves (static indexing)
  float lo[32], hi[32];
#pragma unroll
  for (int jj = 0; jj < 32; ++jj) {
    float tmp = __shfl_xor(r1o[jj], 1);
    lo[jj] = hf ? tmp : r1o[jj];
    hi[jj] = hf ? r1o[jj] : tmp;
  }
  // recon: each half does 64 of 128 k's, 4 accumulators
  float a0 = 0.f, a1 = 0.f, a2 = 0.f, a3 = 0.f;
#pragma unroll 4
  for (int kk = 0; kk < 64; ++kk) {
    const int k = hf * 64 + kk;
    const float* w = W2l + k * 64;
    float s0 = 0.f, s1 = 0.f, s2 = 0.f, s3 = 0.f;
#pragma unroll
    for (int j = 0; j < 8; ++j) {
      s0 += lo[j] * w[j];        s1 += lo[j + 8] * w[j + 8];
      s2 += lo[j + 16] * w[j + 16]; s3 += lo[j + 24] * w[j + 24];
    }
#pragma unroll
    for (int j = 0; j < 8; ++j) {
      s0 += hi[j] * w[32 + j];        s1 += hi[j + 8] * w[40 + j];
      s2 += hi[j + 16] * w[48 + j];   s3 += hi[j + 24] * w[56 + j];
    }
    float s = b2l[k] + (s0 + s1) + (s2 + s3);
    float t = fmaxf(s, 0.f) * W3l[k];
    switch (kk & 3) { case 0: a0 += t; break; case 1: a1 += t; break;
                      case 2: a2 += t; break; default: a3 += t; }
  }
  float own = (a0 + a1) + (a2 + a3);
  float acc2 = br3[0] + own + __shfl_xor(own, 1);
  if (hf == 0) out[32768 + m] = 1.f / (1.f + expf(-acc2));
}

// ---------------------------------------------------------------------------
extern "C" void kernel_launch(void* const* d_in, const int* in_sizes, int n_in,
                              void* d_out, int out_size, void* d_ws, size_t ws_size,
                              hipStream_t stream) {
  const float* x   = (const float*)d_in[0];
  const float* y   = (const float*)d_in[1];
  const float* W1  = (const float*)d_in[2];
  const float* b1  = (const float*)d_in[3];
  const float* Wp  = (const float*)d_in[4];
  const float* bp  = (const float*)d_in[5];
  const float* cbp = (const float*)d_in[6];
  const float* Ws  = (const float*)d_in[7];
  const float* bs  = (const float*)d_in[8];
  const float* cbs = (const float*)d_in[9];
  const float* Wr1 = (const float*)d_in[10];
  const float* br1 = (const float*)d_in[11];
  const float* Wr2 = (const float*)d_in[12];
  const float* br2 = (const float*)d_in[13];
  const float* Wr3 = (const float*)d_in[14];
  const float* br3 = (const float*)d_in[15];
  float* out = (float*)d_out;

  char* ws = (char*)d_ws;
  unsigned short* Apad = (unsigned short*)ws;
  unsigned short* BT   = (unsigned short*)(ws + BT_OFF);
  unsigned short* Pp   = (unsigned short*)(ws + PP_OFF);

  hipLaunchKernelGGL(prep_halo, dim3(516), dim3(256), 0, stream, Wp, BT, Apad);
  hipLaunchKernelGGL(conv1_k, dim3(4096), dim3(256), 0, stream, x, W1, b1, Apad);
  hipLaunchKernelGGL(caps_conv2, dim3(256), dim3(512), 0, stream, Apad, BT, Pp);
  hipLaunchKernelGGL(tail_k3, dim3(256), dim3(256), 0, stream,
                     Pp, y, bp, cbp, Ws, bs, cbs, Wr1, br1, Wr2, br2, Wr3, br3, out);
}